// Round 5
// baseline (2388.359 us; speedup 1.0000x reference)
//
#include <hip/hip_runtime.h>

// LSTMDecoder: B=1024, L=128, H=256, OUT=64, T=256, 2 layers.
// R15: exchange-overlap re-phasing of R14. R14 spent ~12k of 19.1k
// cyc/step on two DEDICATED all-gather phases (other crew idle). R15's
// 3-barrier schedule hides both gathers under compute:
//  A: w0-3 L0 nonlin (gates carried in regs from prev C) + h0 own write
//     + publish;            w4-7 gather h1(t-1) partners.
//  B: w0-3 gather h0(t);    w4-7 hh1 from LDS + out-proj(t-1) (s==0).
//  C: w0-3 hh0*h0(t) -> gates(t+1) (acc live across bar3);
//     w4-7 ih1*h0(t) + nonlin + h1 own write + publish.
// Pipeline: w4-7 C uses decreasing vmcnt(12/8/4/0) tail, VDRAIN (4 pub
// stores only), THEN reissue next-step chunks -> no drain stall at bar3.
// w0-3 keep R14's uniform vmcnt(12) rotation (their A VDRAIN is hidden
// under w4-7's gather). Partner blocks co-located per-XCD via bid=s*32+g
// (perf heuristic only; correctness mapping-independent). Protocol
// unchanged: sc0/sc1 payloads + monotonic agent flags, slot=t&1,
// memset-reset, lgkm-only s_barrier, spin-guard.

typedef float f32x4 __attribute__((ext_vector_type(4)));
typedef short bf16x8 __attribute__((ext_vector_type(8)));
typedef unsigned short u16;
typedef unsigned int u32;
typedef unsigned int u32x4 __attribute__((ext_vector_type(4)));

#define OFF_LH   0          // 32 tiles, KB=4
#define OFF_LC   65536      // 32 tiles, KB=4
#define OFF_IH0  131072     // 64 tiles, KB=4
#define OFF_HH0  262144     // 64 tiles, KB=8
#define OFF_IH1  524288     // 64 tiles, KB=8
#define OFF_HH1  786432     // 64 tiles, KB=8
#define OFF_OUT  1048576    // 4 tiles,  KB=8

#define COMM_B   2228224
#define OBOX(bid,kind,slot) (COMM_B + ((((bid)*2+(kind))*2+(slot)) << 11))
#define FLAG_B   (COMM_B + 2097152)
#define FLAG_OFF(bid,kind) (FLAG_B + (((bid)*2+(kind))*4))
#define SPIN_LIMIT (1<<15)
#define HST 264

__device__ __forceinline__ u16 f2bf(float x){
  unsigned u = __builtin_bit_cast(unsigned, x);
  return (u16)((u + 0x7fffu + ((u >> 16) & 1u)) >> 16);  // RNE
}

__global__ __launch_bounds__(256) void convert_swizzle(
    const float* __restrict__ src, u16* __restrict__ dst,
    int ntiles, int kbshift)
{
  int idx = blockIdx.x * 256 + threadIdx.x;
  int kblocks = 1 << kbshift;
  int n = ntiles << (kbshift + 9);
  if (idx >= n) return;
  int j    = idx & 7;
  int lane = (idx >> 3) & 63;
  int t3   = idx >> 9;
  int kt   = t3 & (kblocks - 1);
  int nt   = t3 >> kbshift;
  int row  = nt * 16 + (lane & 15);
  int k    = kt * 32 + (lane >> 4) * 8 + j;
  dst[idx] = f2bf(src[row * (kblocks * 32) + k]);
}

__device__ __forceinline__ f32x4 mfma16(bf16x8 a, bf16x8 b, f32x4 c){
  return __builtin_amdgcn_mfma_f32_16x16x32_bf16(a, b, c, 0, 0, 0);
}
__device__ __forceinline__ bf16x8 ld8(const u16* p){ return *(const bf16x8*)p; }
__device__ __forceinline__ float sigm(float x){ return 1.f/(1.f + __expf(-x)); }
__device__ __forceinline__ float tanh_f(float x){ return 1.f - 2.f/(__expf(2.f*x) + 1.f); }

#define ISSUE4(Q, seg, kt) \
  asm volatile( \
    "global_load_dwordx4 %0, %4, %8\n\t" \
    "global_load_dwordx4 %1, %5, %8\n\t" \
    "global_load_dwordx4 %2, %6, %8\n\t" \
    "global_load_dwordx4 %3, %7, %8" \
    : "=&v"(Q[0]), "=&v"(Q[1]), "=&v"(Q[2]), "=&v"(Q[3]) \
    : "v"(voffW +           (u32)((kt)*1024)), \
      "v"(voffW + 131072u + (u32)((kt)*1024)), \
      "v"(voffW + 262144u + (u32)((kt)*1024)), \
      "v"(voffW + 393216u + (u32)((kt)*1024)), \
      "s"(seg) \
    : "memory")

#define WAITN(Q, lit) \
  asm volatile("s_waitcnt vmcnt(" lit ")" \
    : "+v"(Q[0]), "+v"(Q[1]), "+v"(Q[2]), "+v"(Q[3]) :: "memory")
#define WAITC(Q) WAITN(Q, "12")

#define MFMA4(afrag, Q) { \
  acc0 = mfma16(afrag, Q[0], acc0); \
  acc1 = mfma16(afrag, Q[1], acc1); \
  acc2 = mfma16(afrag, Q[2], acc2); \
  acc3 = mfma16(afrag, Q[3], acc3); }

#define BARX() asm volatile("s_waitcnt lgkmcnt(0)\n\ts_barrier" ::: "memory")
#define VDRAIN() asm volatile("s_waitcnt vmcnt(0)" ::: "memory")

__device__ __forceinline__ u32 ldflag(const u32* p){
  return __hip_atomic_load(p, __ATOMIC_RELAXED, __HIP_MEMORY_SCOPE_AGENT);
}
__device__ __forceinline__ void stflag(u32* p, u32 v){
  __hip_atomic_store(p, v, __ATOMIC_RELAXED, __HIP_MEMORY_SCOPE_AGENT);
}
__device__ __forceinline__ void pub16(char* p, u32 v){
  asm volatile("global_store_short %0, %1, off sc0 sc1" :: "v"(p), "v"(v) : "memory");
}

__device__ __forceinline__ void gather2(u16* hdst,
    const char* pay0, const char* pay1,
    const u32* pf0, const u32* pf1, int pcnt,
    int ps0, int ps1, int lane, u32 tgt, int* dead)
{
  if (!*dead){
    int gc = 0;
    for(;;){
      u32 a = ldflag(pf0);
      u32 b = (pcnt == 2) ? ldflag(pf1) : tgt;
      if (a >= tgt && b >= tgt) break;
      if (++gc > SPIN_LIMIT){ *dead = 1; break; }
    }
  }
  int base = (lane >> 1)*HST + (lane & 1)*16;
  u32x4 q0, q1, q2, q3;
  if (pcnt == 2){
    asm volatile(
      "global_load_dwordx4 %0, %4, off sc0 sc1\n\t"
      "global_load_dwordx4 %1, %5, off sc0 sc1\n\t"
      "global_load_dwordx4 %2, %6, off sc0 sc1\n\t"
      "global_load_dwordx4 %3, %7, off sc0 sc1"
      : "=&v"(q0), "=&v"(q1), "=&v"(q2), "=&v"(q3)
      : "v"(pay0), "v"(pay0+16), "v"(pay1), "v"(pay1+16)
      : "memory");
    asm volatile("s_waitcnt vmcnt(0)"
      : "+v"(q0), "+v"(q1), "+v"(q2), "+v"(q3) :: "memory");
    *(u32x4*)&hdst[base + ps0*32]     = q0;
    *(u32x4*)&hdst[base + ps0*32 + 8] = q1;
    *(u32x4*)&hdst[base + ps1*32]     = q2;
    *(u32x4*)&hdst[base + ps1*32 + 8] = q3;
  } else {
    asm volatile(
      "global_load_dwordx4 %0, %2, off sc0 sc1\n\t"
      "global_load_dwordx4 %1, %3, off sc0 sc1"
      : "=&v"(q0), "=&v"(q1)
      : "v"(pay0), "v"(pay0+16)
      : "memory");
    asm volatile("s_waitcnt vmcnt(0)" : "+v"(q0), "+v"(q1) :: "memory");
    *(u32x4*)&hdst[base + ps0*32]     = q0;
    *(u32x4*)&hdst[base + ps0*32 + 8] = q1;
  }
}

__global__ __launch_bounds__(512)
void lstm_fused(
    const float* __restrict__ latent,
    const float* __restrict__ b_lh, const float* __restrict__ b_lc,
    const float* __restrict__ b_ih0, const float* __restrict__ b_hh0,
    const float* __restrict__ b_ih1, const float* __restrict__ b_hh1,
    const float* __restrict__ b_out,
    const u16* __restrict__ ws,
    u16* __restrict__ comm,
    float* __restrict__ out)
{
  __shared__ __attribute__((aligned(16))) u16 h0f[2][32*HST];
  __shared__ __attribute__((aligned(16))) u16 h1f[2][32*HST];
  __shared__ __attribute__((aligned(16))) u16 hh1L[64*512];
  __shared__ __attribute__((aligned(16))) u16 lat_s[32*136];

  const u16* __restrict__ w_lh  = ws + OFF_LH;
  const u16* __restrict__ w_lc  = ws + OFF_LC;
  const u16* __restrict__ w_ih0 = ws + OFF_IH0;
  const u16* __restrict__ w_hh0 = ws + OFF_HH0;
  const u16* __restrict__ w_ih1 = ws + OFF_IH1;
  const u16* __restrict__ w_hh1 = ws + OFF_HH1;
  const u16* __restrict__ w_out = ws + OFF_OUT;

  const int tid  = threadIdx.x;
  const int w    = tid >> 6;          // wave 0..7
  const int lane = tid & 63;
  const int col  = lane & 15;
  const int quad = lane >> 4;
  const int bid  = blockIdx.x;        // 0..255
  const int s    = (bid >> 5) & 7;    // column slice (partners stride 32 -> same XCD under round-robin)
  const int g    = bid & 31;          // batch group (32 rows)
  const int rt   = w & 1;
  const int hct  = (w >> 1) & 1;
  const int hrow = quad * 4;
  const int l8   = lane * 8;
  const int ctb  = (s*2 + hct) * 16;
  const u32 voffW = (u32)((s*2 + hct) * 8192 + lane * 16);
  const int hreadR = (rt*16 + col) * HST + quad * 8;
  char* cm = (char*)comm;

  // ---- stage latent (bf16) ----
  for (int i = tid; i < 32*128; i += 512){
    int b = i >> 7, k = i & 127;
    lat_s[b*136 + k] = f2bf(latent[(g*32 + b)*128 + k]);
  }
  __syncthreads();

  // ---- prologue: h(-1) full (local, no exchange) ----
  #pragma unroll 1
  for (int i = 0; i < 8; ++i){
    int task = w*8 + i;
    int layer = task >> 5, rem = task & 31, rtq = rem >> 4, ct = rem & 15;
    int nt = layer*16 + ct;
    float bias = b_lh[nt*16 + col];
    f32x4 a = {bias, bias, bias, bias};
    #pragma unroll
    for (int kt = 0; kt < 4; ++kt){
      bf16x8 la = ld8(&lat_s[(rtq*16 + col)*136 + kt*32 + quad*8]);
      a = mfma16(la, ld8(w_lh + ((nt*4 + kt) << 9) + l8), a);
    }
    u16* dst = layer ? h1f[1] : h0f[1];
    #pragma unroll
    for (int rr = 0; rr < 4; ++rr)
      dst[(rtq*16 + hrow + rr)*HST + ct*16 + col] = f2bf(a[rr]);
  }

  // hh1 slice -> LDS
  for (int i = tid; i < 4096; i += 512){
    int f = i >> 6, l = i & 63;
    int gate = f >> 4, hctf = (f >> 3) & 1, kt = f & 7;
    int nt = gate*16 + s*2 + hctf;
    *(bf16x8*)&hh1L[i*8] = ld8(w_hh1 + ((nt*8 + kt) << 9) + l*8);
  }

  bf16x8 latA[4];
  #pragma unroll
  for (int kt = 0; kt < 4; ++kt)
    latA[kt] = ld8(&lat_s[(rt*16 + col)*136 + kt*32 + quad*8]);

  f32x4 gx0[4] = {};
  float bias1[4] = {};
  float c0[4] = {}, c1[4] = {};
  float bo0 = 0.f, bo1 = 0.f;

  if (w < 4){
    { float bias = b_lc[ctb + col]; f32x4 a = {bias,bias,bias,bias};
      #pragma unroll
      for (int kt = 0; kt < 4; ++kt)
        a = mfma16(latA[kt], ld8(w_lc + (((s*2+hct)*4 + kt) << 9) + l8), a);
      #pragma unroll
      for (int rr = 0; rr < 4; ++rr) c0[rr] = a[rr]; }
    #pragma unroll
    for (int g_ = 0; g_ < 4; ++g_){
      int nt = g_*16 + s*2 + hct;
      float bias = b_ih0[nt*16 + col] + b_hh0[nt*16 + col];
      f32x4 a = {bias, bias, bias, bias};
      #pragma unroll
      for (int kt = 0; kt < 4; ++kt)
        a = mfma16(latA[kt], ld8(w_ih0 + ((nt*4 + kt) << 9) + l8), a);
      gx0[g_] = a;
    }
  } else {
    { float bias = b_lc[256 + ctb + col]; f32x4 a = {bias,bias,bias,bias};
      #pragma unroll
      for (int kt = 0; kt < 4; ++kt)
        a = mfma16(latA[kt], ld8(w_lc + (((16 + s*2+hct)*4 + kt) << 9) + l8), a);
      #pragma unroll
      for (int rr = 0; rr < 4; ++rr) c1[rr] = a[rr]; }
    #pragma unroll
    for (int g_ = 0; g_ < 4; ++g_){
      int nt = g_*16 + s*2 + hct;
      bias1[g_] = b_ih1[nt*16 + col] + b_hh1[nt*16 + col];
    }
    bo0 = b_out[(hct*2 + 0)*16 + col];
    bo1 = b_out[(hct*2 + 1)*16 + col];
  }

  // partner/payload addressing (partner bid = ps*32 + g)
  const int wl = w & 3;
  const int pcnt = (wl < 3) ? 2 : 1;
  int i0 = wl*2, i1 = wl*2 + 1;
  int ps0 = (i0 < s) ? i0 : i0 + 1;
  int ps1 = (i1 < s) ? i1 : i1 + 1;
  if (pcnt == 1) ps1 = ps0;
  const int kindm = (w < 4) ? 0 : 1;
  const char* ppay0 = cm + OBOX(ps0*32 + g, kindm, 0) + lane*32;
  const char* ppay1 = cm + OBOX(ps1*32 + g, kindm, 0) + lane*32;
  const u32* pf0 = (const u32*)(cm + FLAG_OFF(ps0*32 + g, kindm));
  const u32* pf1 = (const u32*)(cm + FLAG_OFF(ps1*32 + g, kindm));
  u32* fmy0 = (u32*)(cm + FLAG_OFF(bid, 0));
  u32* fmy1 = (u32*)(cm + FLAG_OFF(bid, 1));
  char* pub_own = cm + OBOX(bid, kindm, 0)
                + (((rt*16 + hrow)*32 + hct*16 + col) << 1);
  int dead = 0;

  __syncthreads();

  // ---- pipeline prologue + pre-C (gates(0) for w0-3) ----
  bf16x8 Pq0[4], Pq1[4], Pq2[4], Pq3[4];
  f32x4 acc0, acc1, acc2, acc3;
  bf16x8 a0;
  if (w < 4){
    ISSUE4(Pq0, w_hh0, 0); ISSUE4(Pq1, w_hh0, 1);
    ISSUE4(Pq2, w_hh0, 2); ISSUE4(Pq3, w_hh0, 3);
    const u16* h0m1 = h0f[1];
    acc0 = gx0[0]; acc1 = gx0[1]; acc2 = gx0[2]; acc3 = gx0[3];
    WAITC(Pq0); a0 = ld8(&h0m1[hreadR + 0*32]); MFMA4(a0, Pq0); ISSUE4(Pq0, w_hh0, 4);
    WAITC(Pq1); a0 = ld8(&h0m1[hreadR + 1*32]); MFMA4(a0, Pq1); ISSUE4(Pq1, w_hh0, 5);
    WAITC(Pq2); a0 = ld8(&h0m1[hreadR + 2*32]); MFMA4(a0, Pq2); ISSUE4(Pq2, w_hh0, 6);
    WAITC(Pq3); a0 = ld8(&h0m1[hreadR + 3*32]); MFMA4(a0, Pq3); ISSUE4(Pq3, w_hh0, 7);
    WAITC(Pq0); a0 = ld8(&h0m1[hreadR + 4*32]); MFMA4(a0, Pq0); ISSUE4(Pq0, w_hh0, 0);
    WAITC(Pq1); a0 = ld8(&h0m1[hreadR + 5*32]); MFMA4(a0, Pq1); ISSUE4(Pq1, w_hh0, 1);
    WAITC(Pq2); a0 = ld8(&h0m1[hreadR + 6*32]); MFMA4(a0, Pq2); ISSUE4(Pq2, w_hh0, 2);
    WAITC(Pq3); a0 = ld8(&h0m1[hreadR + 7*32]); MFMA4(a0, Pq3); ISSUE4(Pq3, w_hh0, 3);
  } else {
    ISSUE4(Pq0, w_ih1, 0); ISSUE4(Pq1, w_ih1, 1);
    ISSUE4(Pq2, w_ih1, 2); ISSUE4(Pq3, w_ih1, 3);
  }

  for (int t = 0; t < 256; ++t){
    const int p = t & 1;
    u16*       h0c  = h0f[p];        // h0(t)
    u16*       h1c  = h1f[p];        // h1(t)
    u16*       h1pr = h1f[p ^ 1];    // h1(t-1)

    // ======== phase A ========
    if (w < 4){
      // L0 nonlin of carried gates(t); write own h0(t) tile + publish
      #pragma unroll
      for (int rr = 0; rr < 4; ++rr){
        float ii = sigm(acc0[rr]);
        float ff = sigm(acc1[rr]);
        float gg = tanh_f(acc2[rr]);
        float oo = sigm(acc3[rr]);
        float c = ff*c0[rr] + ii*gg;
        c0[rr] = c;
        u16 hb = f2bf(oo * tanh_f(c));
        h0c[(rt*16 + hrow + rr)*HST + ctb + col] = hb;
        pub16(pub_own + (p << 11) + rr*64, (u32)hb);
      }
      VDRAIN();   // payload stores + leftover weight loads (hidden under w4-7 gather)
    } else if (t > 0){
      // gather h1(t-1) partners into h1f[p^1]
      if (w == 4 && lane == 0) stflag(fmy1, (u32)t);
      gather2(h1pr, ppay0 + ((p^1) << 11), ppay1 + ((p^1) << 11),
              pf0, pf1, pcnt, ps0, ps1, lane, (u32)t, &dead);
    }
    BARX();   // bar1: h0(t) own tiles + h1(t-1) full visible; h0 payloads drained

    // ======== phase B ========
    if (w < 4){
      if (w == 0 && lane == 0) stflag(fmy0, (u32)(t+1));
      gather2(h0c, ppay0 + (p << 11), ppay1 + (p << 11),
              pf0, pf1, pcnt, ps0, ps1, lane, (u32)(t+1), &dead);
    } else {
      // hh1 from LDS-resident w_hh1 over full h1(t-1)
      acc0 = (f32x4){bias1[0],bias1[0],bias1[0],bias1[0]};
      acc1 = (f32x4){bias1[1],bias1[1],bias1[1],bias1[1]};
      acc2 = (f32x4){bias1[2],bias1[2],bias1[2],bias1[2]};
      acc3 = (f32x4){bias1[3],bias1[3],bias1[3],bias1[3]};
      #pragma unroll
      for (int kt = 0; kt < 8; ++kt){
        bf16x8 af = ld8(&h1pr[hreadR + kt*32]);
        acc0 = mfma16(af, ld8(&hh1L[((0*2 + hct)*8 + kt)*512 + l8]), acc0);
        acc1 = mfma16(af, ld8(&hh1L[((1*2 + hct)*8 + kt)*512 + l8]), acc1);
        acc2 = mfma16(af, ld8(&hh1L[((2*2 + hct)*8 + kt)*512 + l8]), acc2);
        acc3 = mfma16(af, ld8(&hh1L[((3*2 + hct)*8 + kt)*512 + l8]), acc3);
      }
      if (s == 0 && t > 0){
        // out-proj for step t-1 from full h1(t-1)
        f32x4 o0 = {bo0, bo0, bo0, bo0};
        f32x4 o1 = {bo1, bo1, bo1, bo1};
        #pragma unroll
        for (int kt = 0; kt < 8; ++kt){
          bf16x8 af = ld8(&h1pr[hreadR + kt*32]);
          o0 = mfma16(af, ld8(w_out + (((hct*2 + 0)*8 + kt) << 9) + l8), o0);
          o1 = mfma16(af, ld8(w_out + (((hct*2 + 1)*8 + kt) << 9) + l8), o1);
        }
        #pragma unroll
        for (int rr = 0; rr < 4; ++rr){
          int b = g*32 + rt*16 + hrow + rr;
          __builtin_nontemporal_store(o0[rr], &out[(b*256 + (t-1))*64 + (hct*2+0)*16 + col]);
          __builtin_nontemporal_store(o1[rr], &out[(b*256 + (t-1))*64 + (hct*2+1)*16 + col]);
        }
      }
    }
    BARX();   // bar2: h0(t) full in LDS

    // ======== phase C ========
    if (w < 4){
      // gates(t+1) = gx0 + w_hh0 * h0(t); accs carried across bar3 into next A
      acc0 = gx0[0]; acc1 = gx0[1]; acc2 = gx0[2]; acc3 = gx0[3];
      WAITC(Pq0); a0 = ld8(&h0c[hreadR + 0*32]); MFMA4(a0, Pq0); ISSUE4(Pq0, w_hh0, 4);
      WAITC(Pq1); a0 = ld8(&h0c[hreadR + 1*32]); MFMA4(a0, Pq1); ISSUE4(Pq1, w_hh0, 5);
      WAITC(Pq2); a0 = ld8(&h0c[hreadR + 2*32]); MFMA4(a0, Pq2); ISSUE4(Pq2, w_hh0, 6);
      WAITC(Pq3); a0 = ld8(&h0c[hreadR + 3*32]); MFMA4(a0, Pq3); ISSUE4(Pq3, w_hh0, 7);
      WAITC(Pq0); a0 = ld8(&h0c[hreadR + 4*32]); MFMA4(a0, Pq0); ISSUE4(Pq0, w_hh0, 0); // next step
      WAITC(Pq1); a0 = ld8(&h0c[hreadR + 5*32]); MFMA4(a0, Pq1); ISSUE4(Pq1, w_hh0, 1); // next step
      WAITC(Pq2); a0 = ld8(&h0c[hreadR + 6*32]); MFMA4(a0, Pq2); ISSUE4(Pq2, w_hh0, 2); // next step
      WAITC(Pq3); a0 = ld8(&h0c[hreadR + 7*32]); MFMA4(a0, Pq3); ISSUE4(Pq3, w_hh0, 3); // next step
    } else {
      // ih1 over full h0(t); decreasing tail so VDRAIN sees only pub stores
      WAITC(Pq0);      a0 = ld8(&h0c[hreadR + 0*32]); MFMA4(a0, Pq0); ISSUE4(Pq0, w_ih1, 4);
      WAITC(Pq1);      a0 = ld8(&h0c[hreadR + 1*32]); MFMA4(a0, Pq1); ISSUE4(Pq1, w_ih1, 5);
      WAITC(Pq2);      a0 = ld8(&h0c[hreadR + 2*32]); MFMA4(a0, Pq2); ISSUE4(Pq2, w_ih1, 6);
      WAITC(Pq3);      a0 = ld8(&h0c[hreadR + 3*32]); MFMA4(a0, Pq3); ISSUE4(Pq3, w_ih1, 7);
      WAITC(Pq0);      a0 = ld8(&h0c[hreadR + 4*32]); MFMA4(a0, Pq0);
      WAITN(Pq1, "8"); a0 = ld8(&h0c[hreadR + 5*32]); MFMA4(a0, Pq1);
      WAITN(Pq2, "4"); a0 = ld8(&h0c[hreadR + 6*32]); MFMA4(a0, Pq2);
      WAITN(Pq3, "0"); a0 = ld8(&h0c[hreadR + 7*32]); MFMA4(a0, Pq3);
      #pragma unroll
      for (int rr = 0; rr < 4; ++rr){
        float ii = sigm(acc0[rr]);
        float ff = sigm(acc1[rr]);
        float gg = tanh_f(acc2[rr]);
        float oo = sigm(acc3[rr]);
        float c = ff*c1[rr] + ii*gg;
        c1[rr] = c;
        u16 hb = f2bf(oo * tanh_f(c));
        h1c[(rt*16 + hrow + rr)*HST + ctb + col] = hb;
        pub16(pub_own + (p << 11) + rr*64, (u32)hb);
      }
      VDRAIN();  // only 4 pub stores outstanding
      ISSUE4(Pq0, w_ih1, 0); ISSUE4(Pq1, w_ih1, 1);  // next step
      ISSUE4(Pq2, w_ih1, 2); ISSUE4(Pq3, w_ih1, 3);
    }
    BARX();   // bar3: h1(t) own tiles in LDS, h1 payloads drained
  }

  // ---- epilogue: gather h1(255), then out(255) ----
  if (w >= 4){
    if (w == 4 && lane == 0) stflag(fmy1, 256u);
    gather2(h1f[1], ppay0 + (1 << 11), ppay1 + (1 << 11),
            pf0, pf1, pcnt, ps0, ps1, lane, 256u, &dead);
  }
  BARX();
  if (s == 0 && w >= 4){
    const u16* h1fin = h1f[1];
    f32x4 o0 = {bo0, bo0, bo0, bo0};
    f32x4 o1 = {bo1, bo1, bo1, bo1};
    #pragma unroll
    for (int kt = 0; kt < 8; ++kt){
      bf16x8 af = ld8(&h1fin[hreadR + kt*32]);
      o0 = mfma16(af, ld8(w_out + (((hct*2 + 0)*8 + kt) << 9) + l8), o0);
      o1 = mfma16(af, ld8(w_out + (((hct*2 + 1)*8 + kt) << 9) + l8), o1);
    }
    #pragma unroll
    for (int rr = 0; rr < 4; ++rr){
      int b = g*32 + rt*16 + hrow + rr;
      __builtin_nontemporal_store(o0[rr], &out[(b*256 + 255)*64 + (hct*2+0)*16 + col]);
      __builtin_nontemporal_store(o1[rr], &out[(b*256 + 255)*64 + (hct*2+1)*16 + col]);
    }
  }
}

extern "C" void kernel_launch(void* const* d_in, const int* in_sizes, int n_in,
                              void* d_out, int out_size, void* d_ws, size_t ws_size,
                              hipStream_t stream)
{
  (void)in_sizes; (void)n_in; (void)out_size; (void)ws_size;
  const float* latent = (const float*)d_in[0];
  const float* w_lh   = (const float*)d_in[1];
  const float* b_lh   = (const float*)d_in[2];
  const float* w_lc   = (const float*)d_in[3];
  const float* b_lc   = (const float*)d_in[4];
  const float* w_ih0  = (const float*)d_in[5];
  const float* w_hh0  = (const float*)d_in[6];
  const float* b_ih0  = (const float*)d_in[7];
  const float* b_hh0  = (const float*)d_in[8];
  const float* w_ih1  = (const float*)d_in[9];
  const float* w_hh1  = (const float*)d_in[10];
  const float* b_ih1  = (const float*)d_in[11];
  const float* b_hh1  = (const float*)d_in[12];
  const float* w_out  = (const float*)d_in[13];
  const float* b_out  = (const float*)d_in[14];
  u16* ws = (u16*)d_ws;
  float* out = (float*)d_out;

  auto cvt = [&](const float* src, int off, int ntiles, int kbshift){
    int n = ntiles << (kbshift + 9);
    convert_swizzle<<<dim3((n + 255)/256), dim3(256), 0, stream>>>(src, ws + off, ntiles, kbshift);
  };
  cvt(w_lh,  OFF_LH,  32, 2);
  cvt(w_lc,  OFF_LC,  32, 2);
  cvt(w_ih0, OFF_IH0, 64, 2);
  cvt(w_hh0, OFF_HH0, 64, 3);
  cvt(w_ih1, OFF_IH1, 64, 3);
  cvt(w_hh1, OFF_HH1, 64, 3);
  cvt(w_out, OFF_OUT, 4, 3);

  hipMemsetAsync((char*)d_ws + FLAG_B, 0, 256*2*4, stream);

  lstm_fused<<<dim3(256), dim3(512), 0, stream>>>(latent, b_lh, b_lc, b_ih0, b_hh0,
                                                  b_ih1, b_hh1, b_out, ws, ws, out);
}

// Round 6
// 1820.587 us; speedup vs baseline: 1.3119x; 1.3119x over previous
//
#include <hip/hip_runtime.h>

// LSTMDecoder: B=1024, L=128, H=256, OUT=64, T=256, 2 layers.
// R16: ONE exchange per step (R14/R15 had two). R15 regressed (2049->2325)
// because out-proj stacked onto w4-7's compute phase made s==0 blocks the
// per-group straggler under flag-lockstep, and partners-on-one-XCD
// concentrated traffic. R16 reverts both and restructures to a single
// gather phase per step:
//  A: w0-3 nonlin gates(t) (carried from prev X) -> h0(t) own tile + pub;
//     w4-7 (s==0, t>=2): out-proj(t-2) from h1f[p] (full h1(t-2)) - idle slot.
//  G: one combined flag (kind0, value t+1) covers h0(t) pubs (drained in A)
//     AND h1(t-1) pubs (drained in prev X). w0-3 gather partner h0(t);
//     w4-7 gather partner h1(t-1). ONE L3 round-trip/step.
//  X: w0-3 hh0*h0(t) -> gates(t+1) carried across barrier (+8 hh0 reissues);
//     w4-7 hh1*h1(t-1) (LDS-resident) + ih1*h0(t) (streamed, decreasing
//     vmcnt tail) + nonlin -> h1(t) own + pub + VDRAIN + reissue.
// Slot safety: gather at G(t+1) needs partner flag t+2, set only after the
// partner passed G(t) -> 2-step separation before any slot overwrite, for
// both payload kinds. bid mapping back to R14 (s=bid&7: partners spread
// across XCDs). Protocol otherwise unchanged (sc0/sc1 payloads, monotonic
// agent flags, memset reset, lgkm-only s_barrier, spin-guard).

typedef float f32x4 __attribute__((ext_vector_type(4)));
typedef short bf16x8 __attribute__((ext_vector_type(8)));
typedef unsigned short u16;
typedef unsigned int u32;
typedef unsigned int u32x4 __attribute__((ext_vector_type(4)));

#define OFF_LH   0          // 32 tiles, KB=4
#define OFF_LC   65536      // 32 tiles, KB=4
#define OFF_IH0  131072     // 64 tiles, KB=4
#define OFF_HH0  262144     // 64 tiles, KB=8
#define OFF_IH1  524288     // 64 tiles, KB=8
#define OFF_HH1  786432     // 64 tiles, KB=8
#define OFF_OUT  1048576    // 4 tiles,  KB=8

#define COMM_B   2228224
#define OBOX(bid,kind,slot) (COMM_B + ((((bid)*2+(kind))*2+(slot)) << 11))
#define FLAG_B   (COMM_B + 2097152)
#define FLAG_OFF(bid,kind) (FLAG_B + (((bid)*2+(kind))*4))
#define SPIN_LIMIT (1<<15)
#define HST 264

__device__ __forceinline__ u16 f2bf(float x){
  unsigned u = __builtin_bit_cast(unsigned, x);
  return (u16)((u + 0x7fffu + ((u >> 16) & 1u)) >> 16);  // RNE
}

__global__ __launch_bounds__(256) void convert_swizzle(
    const float* __restrict__ src, u16* __restrict__ dst,
    int ntiles, int kbshift)
{
  int idx = blockIdx.x * 256 + threadIdx.x;
  int kblocks = 1 << kbshift;
  int n = ntiles << (kbshift + 9);
  if (idx >= n) return;
  int j    = idx & 7;
  int lane = (idx >> 3) & 63;
  int t3   = idx >> 9;
  int kt   = t3 & (kblocks - 1);
  int nt   = t3 >> kbshift;
  int row  = nt * 16 + (lane & 15);
  int k    = kt * 32 + (lane >> 4) * 8 + j;
  dst[idx] = f2bf(src[row * (kblocks * 32) + k]);
}

__device__ __forceinline__ f32x4 mfma16(bf16x8 a, bf16x8 b, f32x4 c){
  return __builtin_amdgcn_mfma_f32_16x16x32_bf16(a, b, c, 0, 0, 0);
}
__device__ __forceinline__ bf16x8 ld8(const u16* p){ return *(const bf16x8*)p; }
__device__ __forceinline__ float sigm(float x){ return 1.f/(1.f + __expf(-x)); }
__device__ __forceinline__ float tanh_f(float x){ return 1.f - 2.f/(__expf(2.f*x) + 1.f); }

#define ISSUE4(Q, seg, kt) \
  asm volatile( \
    "global_load_dwordx4 %0, %4, %8\n\t" \
    "global_load_dwordx4 %1, %5, %8\n\t" \
    "global_load_dwordx4 %2, %6, %8\n\t" \
    "global_load_dwordx4 %3, %7, %8" \
    : "=&v"(Q[0]), "=&v"(Q[1]), "=&v"(Q[2]), "=&v"(Q[3]) \
    : "v"(voffW +           (u32)((kt)*1024)), \
      "v"(voffW + 131072u + (u32)((kt)*1024)), \
      "v"(voffW + 262144u + (u32)((kt)*1024)), \
      "v"(voffW + 393216u + (u32)((kt)*1024)), \
      "s"(seg) \
    : "memory")

#define WAITN(Q, lit) \
  asm volatile("s_waitcnt vmcnt(" lit ")" \
    : "+v"(Q[0]), "+v"(Q[1]), "+v"(Q[2]), "+v"(Q[3]) :: "memory")
#define WAITC(Q) WAITN(Q, "12")

#define MFMA4(afrag, Q) { \
  acc0 = mfma16(afrag, Q[0], acc0); \
  acc1 = mfma16(afrag, Q[1], acc1); \
  acc2 = mfma16(afrag, Q[2], acc2); \
  acc3 = mfma16(afrag, Q[3], acc3); }

#define BARX() asm volatile("s_waitcnt lgkmcnt(0)\n\ts_barrier" ::: "memory")
#define VDRAIN() asm volatile("s_waitcnt vmcnt(0)" ::: "memory")

__device__ __forceinline__ u32 ldflag(const u32* p){
  return __hip_atomic_load(p, __ATOMIC_RELAXED, __HIP_MEMORY_SCOPE_AGENT);
}
__device__ __forceinline__ void stflag(u32* p, u32 v){
  __hip_atomic_store(p, v, __ATOMIC_RELAXED, __HIP_MEMORY_SCOPE_AGENT);
}
__device__ __forceinline__ void pub16(char* p, u32 v){
  asm volatile("global_store_short %0, %1, off sc0 sc1" :: "v"(p), "v"(v) : "memory");
}

__device__ __forceinline__ void gather2(u16* hdst,
    const char* pay0, const char* pay1,
    const u32* pf0, const u32* pf1, int pcnt,
    int ps0, int ps1, int lane, u32 tgt, int* dead)
{
  if (!*dead){
    int gc = 0;
    for(;;){
      u32 a = ldflag(pf0);
      u32 b = (pcnt == 2) ? ldflag(pf1) : tgt;
      if (a >= tgt && b >= tgt) break;
      if (++gc > SPIN_LIMIT){ *dead = 1; break; }
    }
  }
  int base = (lane >> 1)*HST + (lane & 1)*16;
  u32x4 q0, q1, q2, q3;
  if (pcnt == 2){
    asm volatile(
      "global_load_dwordx4 %0, %4, off sc0 sc1\n\t"
      "global_load_dwordx4 %1, %5, off sc0 sc1\n\t"
      "global_load_dwordx4 %2, %6, off sc0 sc1\n\t"
      "global_load_dwordx4 %3, %7, off sc0 sc1"
      : "=&v"(q0), "=&v"(q1), "=&v"(q2), "=&v"(q3)
      : "v"(pay0), "v"(pay0+16), "v"(pay1), "v"(pay1+16)
      : "memory");
    asm volatile("s_waitcnt vmcnt(0)"
      : "+v"(q0), "+v"(q1), "+v"(q2), "+v"(q3) :: "memory");
    *(u32x4*)&hdst[base + ps0*32]     = q0;
    *(u32x4*)&hdst[base + ps0*32 + 8] = q1;
    *(u32x4*)&hdst[base + ps1*32]     = q2;
    *(u32x4*)&hdst[base + ps1*32 + 8] = q3;
  } else {
    asm volatile(
      "global_load_dwordx4 %0, %2, off sc0 sc1\n\t"
      "global_load_dwordx4 %1, %3, off sc0 sc1"
      : "=&v"(q0), "=&v"(q1)
      : "v"(pay0), "v"(pay0+16)
      : "memory");
    asm volatile("s_waitcnt vmcnt(0)" : "+v"(q0), "+v"(q1) :: "memory");
    *(u32x4*)&hdst[base + ps0*32]     = q0;
    *(u32x4*)&hdst[base + ps0*32 + 8] = q1;
  }
}

__global__ __launch_bounds__(512)
void lstm_fused(
    const float* __restrict__ latent,
    const float* __restrict__ b_lh, const float* __restrict__ b_lc,
    const float* __restrict__ b_ih0, const float* __restrict__ b_hh0,
    const float* __restrict__ b_ih1, const float* __restrict__ b_hh1,
    const float* __restrict__ b_out,
    const u16* __restrict__ ws,
    u16* __restrict__ comm,
    float* __restrict__ out)
{
  __shared__ __attribute__((aligned(16))) u16 h0f[2][32*HST];
  __shared__ __attribute__((aligned(16))) u16 h1f[2][32*HST];
  __shared__ __attribute__((aligned(16))) u16 hh1L[64*512];
  __shared__ __attribute__((aligned(16))) u16 lat_s[32*136];

  const u16* __restrict__ w_lh  = ws + OFF_LH;
  const u16* __restrict__ w_lc  = ws + OFF_LC;
  const u16* __restrict__ w_ih0 = ws + OFF_IH0;
  const u16* __restrict__ w_hh0 = ws + OFF_HH0;
  const u16* __restrict__ w_ih1 = ws + OFF_IH1;
  const u16* __restrict__ w_hh1 = ws + OFF_HH1;
  const u16* __restrict__ w_out = ws + OFF_OUT;

  const int tid  = threadIdx.x;
  const int w    = tid >> 6;          // wave 0..7
  const int lane = tid & 63;
  const int col  = lane & 15;
  const int quad = lane >> 4;
  const int bid  = blockIdx.x;        // 0..255
  const int s    = bid & 7;           // column slice (R14 mapping: partners spread over XCDs)
  const int g    = bid >> 3;          // batch group (32 rows)
  const int rt   = w & 1;
  const int hct  = (w >> 1) & 1;
  const int hrow = quad * 4;
  const int l8   = lane * 8;
  const int ctb  = (s*2 + hct) * 16;
  const u32 voffW = (u32)((s*2 + hct) * 8192 + lane * 16);
  const int hreadR = (rt*16 + col) * HST + quad * 8;
  char* cm = (char*)comm;

  // ---- stage latent (bf16) ----
  for (int i = tid; i < 32*128; i += 512){
    int b = i >> 7, k = i & 127;
    lat_s[b*136 + k] = f2bf(latent[(g*32 + b)*128 + k]);
  }
  __syncthreads();

  // ---- prologue: h(-1) full (local, no exchange) ----
  #pragma unroll 1
  for (int i = 0; i < 8; ++i){
    int task = w*8 + i;
    int layer = task >> 5, rem = task & 31, rtq = rem >> 4, ct = rem & 15;
    int nt = layer*16 + ct;
    float bias = b_lh[nt*16 + col];
    f32x4 a = {bias, bias, bias, bias};
    #pragma unroll
    for (int kt = 0; kt < 4; ++kt){
      bf16x8 la = ld8(&lat_s[(rtq*16 + col)*136 + kt*32 + quad*8]);
      a = mfma16(la, ld8(w_lh + ((nt*4 + kt) << 9) + l8), a);
    }
    u16* dst = layer ? h1f[1] : h0f[1];
    #pragma unroll
    for (int rr = 0; rr < 4; ++rr)
      dst[(rtq*16 + hrow + rr)*HST + ct*16 + col] = f2bf(a[rr]);
  }

  // hh1 slice -> LDS
  for (int i = tid; i < 4096; i += 512){
    int f = i >> 6, l = i & 63;
    int gate = f >> 4, hctf = (f >> 3) & 1, kt = f & 7;
    int nt = gate*16 + s*2 + hctf;
    *(bf16x8*)&hh1L[i*8] = ld8(w_hh1 + ((nt*8 + kt) << 9) + l*8);
  }

  bf16x8 latA[4];
  #pragma unroll
  for (int kt = 0; kt < 4; ++kt)
    latA[kt] = ld8(&lat_s[(rt*16 + col)*136 + kt*32 + quad*8]);

  f32x4 gx0[4] = {};
  float bias1[4] = {};
  float c0[4] = {}, c1[4] = {};
  const float bo0 = b_out[(hct*2 + 0)*16 + col];
  const float bo1 = b_out[(hct*2 + 1)*16 + col];

  if (w < 4){
    { float bias = b_lc[ctb + col]; f32x4 a = {bias,bias,bias,bias};
      #pragma unroll
      for (int kt = 0; kt < 4; ++kt)
        a = mfma16(latA[kt], ld8(w_lc + (((s*2+hct)*4 + kt) << 9) + l8), a);
      #pragma unroll
      for (int rr = 0; rr < 4; ++rr) c0[rr] = a[rr]; }
    #pragma unroll
    for (int g_ = 0; g_ < 4; ++g_){
      int nt = g_*16 + s*2 + hct;
      float bias = b_ih0[nt*16 + col] + b_hh0[nt*16 + col];
      f32x4 a = {bias, bias, bias, bias};
      #pragma unroll
      for (int kt = 0; kt < 4; ++kt)
        a = mfma16(latA[kt], ld8(w_ih0 + ((nt*4 + kt) << 9) + l8), a);
      gx0[g_] = a;
    }
  } else {
    { float bias = b_lc[256 + ctb + col]; f32x4 a = {bias,bias,bias,bias};
      #pragma unroll
      for (int kt = 0; kt < 4; ++kt)
        a = mfma16(latA[kt], ld8(w_lc + (((16 + s*2+hct)*4 + kt) << 9) + l8), a);
      #pragma unroll
      for (int rr = 0; rr < 4; ++rr) c1[rr] = a[rr]; }
    #pragma unroll
    for (int g_ = 0; g_ < 4; ++g_){
      int nt = g_*16 + s*2 + hct;
      bias1[g_] = b_ih1[nt*16 + col] + b_hh1[nt*16 + col];
    }
  }

  // partner/payload addressing (partner bid = g*8 + ps); flag = kind0 only
  const int wl = w & 3;
  const int pcnt = (wl < 3) ? 2 : 1;
  int i0 = wl*2, i1 = wl*2 + 1;
  int ps0 = (i0 < s) ? i0 : i0 + 1;
  int ps1 = (i1 < s) ? i1 : i1 + 1;
  if (pcnt == 1) ps1 = ps0;
  const int kindm = (w < 4) ? 0 : 1;
  const char* ppay0 = cm + OBOX(g*8 + ps0, kindm, 0) + lane*32;
  const char* ppay1 = cm + OBOX(g*8 + ps1, kindm, 0) + lane*32;
  const u32* pf0 = (const u32*)(cm + FLAG_OFF(g*8 + ps0, 0));
  const u32* pf1 = (const u32*)(cm + FLAG_OFF(g*8 + ps1, 0));
  u32* fmy0 = (u32*)(cm + FLAG_OFF(bid, 0));
  char* pub_own = cm + OBOX(bid, kindm, 0)
                + (((rt*16 + hrow)*32 + hct*16 + col) << 1);
  int dead = 0;

  __syncthreads();

  // ---- pipeline prologue + pre-X (gates(0) for w0-3) ----
  bf16x8 Pq0[4], Pq1[4], Pq2[4], Pq3[4];
  f32x4 acc0, acc1, acc2, acc3;
  bf16x8 a0;
  if (w < 4){
    ISSUE4(Pq0, w_hh0, 0); ISSUE4(Pq1, w_hh0, 1);
    ISSUE4(Pq2, w_hh0, 2); ISSUE4(Pq3, w_hh0, 3);
    const u16* h0m1 = h0f[1];
    acc0 = gx0[0]; acc1 = gx0[1]; acc2 = gx0[2]; acc3 = gx0[3];
    WAITC(Pq0); a0 = ld8(&h0m1[hreadR + 0*32]); MFMA4(a0, Pq0); ISSUE4(Pq0, w_hh0, 4);
    WAITC(Pq1); a0 = ld8(&h0m1[hreadR + 1*32]); MFMA4(a0, Pq1); ISSUE4(Pq1, w_hh0, 5);
    WAITC(Pq2); a0 = ld8(&h0m1[hreadR + 2*32]); MFMA4(a0, Pq2); ISSUE4(Pq2, w_hh0, 6);
    WAITC(Pq3); a0 = ld8(&h0m1[hreadR + 3*32]); MFMA4(a0, Pq3); ISSUE4(Pq3, w_hh0, 7);
    WAITC(Pq0); a0 = ld8(&h0m1[hreadR + 4*32]); MFMA4(a0, Pq0); ISSUE4(Pq0, w_hh0, 0);
    WAITC(Pq1); a0 = ld8(&h0m1[hreadR + 5*32]); MFMA4(a0, Pq1); ISSUE4(Pq1, w_hh0, 1);
    WAITC(Pq2); a0 = ld8(&h0m1[hreadR + 6*32]); MFMA4(a0, Pq2); ISSUE4(Pq2, w_hh0, 2);
    WAITC(Pq3); a0 = ld8(&h0m1[hreadR + 7*32]); MFMA4(a0, Pq3); ISSUE4(Pq3, w_hh0, 3);
  } else {
    ISSUE4(Pq0, w_ih1, 0); ISSUE4(Pq1, w_ih1, 1);
    ISSUE4(Pq2, w_ih1, 2); ISSUE4(Pq3, w_ih1, 3);
  }

  for (int t = 0; t < 256; ++t){
    const int p = t & 1;
    u16*       h0c  = h0f[p];        // h0(t)
    u16*       h1c  = h1f[p];        // h1(t)
    u16*       h1pr = h1f[p ^ 1];    // h1(t-1)

    // ======== phase A ========
    if (w < 4){
      // L0 nonlin of carried gates(t); write own h0(t) tile + publish
      #pragma unroll
      for (int rr = 0; rr < 4; ++rr){
        float ii = sigm(acc0[rr]);
        float ff = sigm(acc1[rr]);
        float gg = tanh_f(acc2[rr]);
        float oo = sigm(acc3[rr]);
        float c = ff*c0[rr] + ii*gg;
        c0[rr] = c;
        u16 hb = f2bf(oo * tanh_f(c));
        h0c[(rt*16 + hrow + rr)*HST + ctb + col] = hb;
        pub16(pub_own + (p << 11) + rr*64, (u32)hb);
      }
      VDRAIN();   // pub stores (+ old in-flight chunks land in regs)
    } else if (s == 0 && t >= 2){
      // out-proj(t-2) from h1f[p] (full h1(t-2)); idle slot, parallel waves
      const u16* h1o = h1f[p];
      f32x4 o0 = {bo0, bo0, bo0, bo0};
      f32x4 o1 = {bo1, bo1, bo1, bo1};
      #pragma unroll
      for (int kt = 0; kt < 8; ++kt){
        bf16x8 af = ld8(&h1o[hreadR + kt*32]);
        o0 = mfma16(af, ld8(w_out + (((hct*2 + 0)*8 + kt) << 9) + l8), o0);
        o1 = mfma16(af, ld8(w_out + (((hct*2 + 1)*8 + kt) << 9) + l8), o1);
      }
      #pragma unroll
      for (int rr = 0; rr < 4; ++rr){
        int b = g*32 + rt*16 + hrow + rr;
        __builtin_nontemporal_store(o0[rr], &out[(b*256 + (t-2))*64 + (hct*2+0)*16 + col]);
        __builtin_nontemporal_store(o1[rr], &out[(b*256 + (t-2))*64 + (hct*2+1)*16 + col]);
      }
    }
    BARX();   // bar1: h0(t) own tiles in LDS; h0(t) + h1(t-1) pubs all drained

    // ======== phase G: single exchange ========
    if (w == 0 && lane == 0) stflag(fmy0, (u32)(t+1));
    if (w < 4){
      gather2(h0c, ppay0 + (p << 11), ppay1 + (p << 11),
              pf0, pf1, pcnt, ps0, ps1, lane, (u32)(t+1), &dead);
    } else if (t > 0){
      gather2(h1pr, ppay0 + ((p^1) << 11), ppay1 + ((p^1) << 11),
              pf0, pf1, pcnt, ps0, ps1, lane, (u32)(t+1), &dead);
    }
    BARX();   // bar2: h0(t) and h1(t-1) full in LDS

    // ======== phase X ========
    if (w < 4){
      // gates(t+1) = gx0 + w_hh0 * h0(t); accs carried across bar3 into next A
      acc0 = gx0[0]; acc1 = gx0[1]; acc2 = gx0[2]; acc3 = gx0[3];
      WAITC(Pq0); a0 = ld8(&h0c[hreadR + 0*32]); MFMA4(a0, Pq0); ISSUE4(Pq0, w_hh0, 4);
      WAITC(Pq1); a0 = ld8(&h0c[hreadR + 1*32]); MFMA4(a0, Pq1); ISSUE4(Pq1, w_hh0, 5);
      WAITC(Pq2); a0 = ld8(&h0c[hreadR + 2*32]); MFMA4(a0, Pq2); ISSUE4(Pq2, w_hh0, 6);
      WAITC(Pq3); a0 = ld8(&h0c[hreadR + 3*32]); MFMA4(a0, Pq3); ISSUE4(Pq3, w_hh0, 7);
      WAITC(Pq0); a0 = ld8(&h0c[hreadR + 4*32]); MFMA4(a0, Pq0); ISSUE4(Pq0, w_hh0, 0); // next step
      WAITC(Pq1); a0 = ld8(&h0c[hreadR + 5*32]); MFMA4(a0, Pq1); ISSUE4(Pq1, w_hh0, 1); // next step
      WAITC(Pq2); a0 = ld8(&h0c[hreadR + 6*32]); MFMA4(a0, Pq2); ISSUE4(Pq2, w_hh0, 2); // next step
      WAITC(Pq3); a0 = ld8(&h0c[hreadR + 7*32]); MFMA4(a0, Pq3); ISSUE4(Pq3, w_hh0, 3); // next step
    } else {
      // hh1 from LDS-resident w_hh1 over full h1(t-1)
      acc0 = (f32x4){bias1[0],bias1[0],bias1[0],bias1[0]};
      acc1 = (f32x4){bias1[1],bias1[1],bias1[1],bias1[1]};
      acc2 = (f32x4){bias1[2],bias1[2],bias1[2],bias1[2]};
      acc3 = (f32x4){bias1[3],bias1[3],bias1[3],bias1[3]};
      #pragma unroll
      for (int kt = 0; kt < 8; ++kt){
        bf16x8 af = ld8(&h1pr[hreadR + kt*32]);
        acc0 = mfma16(af, ld8(&hh1L[((0*2 + hct)*8 + kt)*512 + l8]), acc0);
        acc1 = mfma16(af, ld8(&hh1L[((1*2 + hct)*8 + kt)*512 + l8]), acc1);
        acc2 = mfma16(af, ld8(&hh1L[((2*2 + hct)*8 + kt)*512 + l8]), acc2);
        acc3 = mfma16(af, ld8(&hh1L[((3*2 + hct)*8 + kt)*512 + l8]), acc3);
      }
      // ih1 over full h0(t); decreasing tail so VDRAIN sees only pub stores
      WAITC(Pq0);      a0 = ld8(&h0c[hreadR + 0*32]); MFMA4(a0, Pq0); ISSUE4(Pq0, w_ih1, 4);
      WAITC(Pq1);      a0 = ld8(&h0c[hreadR + 1*32]); MFMA4(a0, Pq1); ISSUE4(Pq1, w_ih1, 5);
      WAITC(Pq2);      a0 = ld8(&h0c[hreadR + 2*32]); MFMA4(a0, Pq2); ISSUE4(Pq2, w_ih1, 6);
      WAITC(Pq3);      a0 = ld8(&h0c[hreadR + 3*32]); MFMA4(a0, Pq3); ISSUE4(Pq3, w_ih1, 7);
      WAITC(Pq0);      a0 = ld8(&h0c[hreadR + 4*32]); MFMA4(a0, Pq0);
      WAITN(Pq1, "8"); a0 = ld8(&h0c[hreadR + 5*32]); MFMA4(a0, Pq1);
      WAITN(Pq2, "4"); a0 = ld8(&h0c[hreadR + 6*32]); MFMA4(a0, Pq2);
      WAITN(Pq3, "0"); a0 = ld8(&h0c[hreadR + 7*32]); MFMA4(a0, Pq3);
      #pragma unroll
      for (int rr = 0; rr < 4; ++rr){
        float ii = sigm(acc0[rr]);
        float ff = sigm(acc1[rr]);
        float gg = tanh_f(acc2[rr]);
        float oo = sigm(acc3[rr]);
        float c = ff*c1[rr] + ii*gg;
        c1[rr] = c;
        u16 hb = f2bf(oo * tanh_f(c));
        h1c[(rt*16 + hrow + rr)*HST + ctb + col] = hb;
        pub16(pub_own + (p << 11) + rr*64, (u32)hb);
      }
      VDRAIN();  // only 4 pub stores outstanding
      ISSUE4(Pq0, w_ih1, 0); ISSUE4(Pq1, w_ih1, 1);  // next step
      ISSUE4(Pq2, w_ih1, 2); ISSUE4(Pq3, w_ih1, 3);
    }
    BARX();   // bar3: h1(t) own tiles in LDS, h1 pubs drained
  }

  // ---- epilogue: gather h1(255); out(254) and out(255) ----
  if (w == 0 && lane == 0) stflag(fmy0, 257u);
  if (w >= 4){
    gather2(h1f[1], ppay0 + (1 << 11), ppay1 + (1 << 11),
            pf0, pf1, pcnt, ps0, ps1, lane, 257u, &dead);
  } else if (s == 0){
    // out-proj(254) from h1f[0] (full h1(254), gathered at G(255))
    const u16* h1o = h1f[0];
    f32x4 o0 = {bo0, bo0, bo0, bo0};
    f32x4 o1 = {bo1, bo1, bo1, bo1};
    #pragma unroll
    for (int kt = 0; kt < 8; ++kt){
      bf16x8 af = ld8(&h1o[hreadR + kt*32]);
      o0 = mfma16(af, ld8(w_out + (((hct*2 + 0)*8 + kt) << 9) + l8), o0);
      o1 = mfma16(af, ld8(w_out + (((hct*2 + 1)*8 + kt) << 9) + l8), o1);
    }
    #pragma unroll
    for (int rr = 0; rr < 4; ++rr){
      int b = g*32 + rt*16 + hrow + rr;
      __builtin_nontemporal_store(o0[rr], &out[(b*256 + 254)*64 + (hct*2+0)*16 + col]);
      __builtin_nontemporal_store(o1[rr], &out[(b*256 + 254)*64 + (hct*2+1)*16 + col]);
    }
  }
  BARX();
  if (s == 0 && w >= 4){
    const u16* h1fin = h1f[1];
    f32x4 o0 = {bo0, bo0, bo0, bo0};
    f32x4 o1 = {bo1, bo1, bo1, bo1};
    #pragma unroll
    for (int kt = 0; kt < 8; ++kt){
      bf16x8 af = ld8(&h1fin[hreadR + kt*32]);
      o0 = mfma16(af, ld8(w_out + (((hct*2 + 0)*8 + kt) << 9) + l8), o0);
      o1 = mfma16(af, ld8(w_out + (((hct*2 + 1)*8 + kt) << 9) + l8), o1);
    }
    #pragma unroll
    for (int rr = 0; rr < 4; ++rr){
      int b = g*32 + rt*16 + hrow + rr;
      __builtin_nontemporal_store(o0[rr], &out[(b*256 + 255)*64 + (hct*2+0)*16 + col]);
      __builtin_nontemporal_store(o1[rr], &out[(b*256 + 255)*64 + (hct*2+1)*16 + col]);
    }
  }
}

extern "C" void kernel_launch(void* const* d_in, const int* in_sizes, int n_in,
                              void* d_out, int out_size, void* d_ws, size_t ws_size,
                              hipStream_t stream)
{
  (void)in_sizes; (void)n_in; (void)out_size; (void)ws_size;
  const float* latent = (const float*)d_in[0];
  const float* w_lh   = (const float*)d_in[1];
  const float* b_lh   = (const float*)d_in[2];
  const float* w_lc   = (const float*)d_in[3];
  const float* b_lc   = (const float*)d_in[4];
  const float* w_ih0  = (const float*)d_in[5];
  const float* w_hh0  = (const float*)d_in[6];
  const float* b_ih0  = (const float*)d_in[7];
  const float* b_hh0  = (const float*)d_in[8];
  const float* w_ih1  = (const float*)d_in[9];
  const float* w_hh1  = (const float*)d_in[10];
  const float* b_ih1  = (const float*)d_in[11];
  const float* b_hh1  = (const float*)d_in[12];
  const float* w_out  = (const float*)d_in[13];
  const float* b_out  = (const float*)d_in[14];
  u16* ws = (u16*)d_ws;
  float* out = (float*)d_out;

  auto cvt = [&](const float* src, int off, int ntiles, int kbshift){
    int n = ntiles << (kbshift + 9);
    convert_swizzle<<<dim3((n + 255)/256), dim3(256), 0, stream>>>(src, ws + off, ntiles, kbshift);
  };
  cvt(w_lh,  OFF_LH,  32, 2);
  cvt(w_lc,  OFF_LC,  32, 2);
  cvt(w_ih0, OFF_IH0, 64, 2);
  cvt(w_hh0, OFF_HH0, 64, 3);
  cvt(w_ih1, OFF_IH1, 64, 3);
  cvt(w_hh1, OFF_HH1, 64, 3);
  cvt(w_out, OFF_OUT, 4, 3);

  hipMemsetAsync((char*)d_ws + FLAG_B, 0, 256*2*4, stream);

  lstm_fused<<<dim3(256), dim3(512), 0, stream>>>(latent, b_lh, b_lc, b_ih0, b_hh0,
                                                  b_ih1, b_hh1, b_out, ws, ws, out);
}

// Round 8
// 1456.312 us; speedup vs baseline: 1.6400x; 1.2501x over previous
//
#include <hip/hip_runtime.h>

// LSTMDecoder: B=1024, L=128, H=256, OUT=64, T=256, 2 layers.
// R18: 2-phase step {G,bar,X,bar} + per-wave flags posted pre-barrier.
// R17's 16B self-validating records FAILED (absmax 1.79 = the predicted
// tag-visible/data-stale tearing mode) -> revert to R16's PROVEN
// flag+payload protocol. The latency win comes from scheduling instead:
//  - Phase A folded into X: w0-3's X(t) = hh0*h0(t) -> gates(t+1) ->
//    nonlin -> h0(t+1) own tile + pub (R16's proven decreasing-vmcnt-tail
//    + pub + VDRAIN(4 stores) + reissue pattern, now on both crews).
//  - Per-wave flags: each producer wave posts flag[wl] right after its own
//    VDRAIN (covers only its own 4 pub stores), DURING X. Consumer polls a
//    partner's 4 wave-flags with one dwordx4 -> by G time flags are long
//    visible -> first-try hit; serial chain ~= one payload RT.
//  - Slot safety: unchanged transitive proof (writer reaches slot reuse
//    only after gathering from all partners, which requires partners to
//    have consumed the old slot; barriers order crews within a block).
//  - out-proj distributed: block s<4 owns OUT tile s, computed on w0-1 in
//    X from h1(t-2) via 3-deep h1 LDS ring (no straggler crew/block).
// Weight streams unchanged (hh0 on w0-3, ih1 on w4-7, 256KB/step; hh1
// LDS-resident). Spin-guard bounded -> fast wrong answer, never a hang.

typedef float f32x4 __attribute__((ext_vector_type(4)));
typedef short bf16x8 __attribute__((ext_vector_type(8)));
typedef unsigned short u16;
typedef unsigned int u32;
typedef unsigned int u32x4 __attribute__((ext_vector_type(4)));

#define OFF_LH   0          // 32 tiles, KB=4
#define OFF_LC   65536      // 32 tiles, KB=4
#define OFF_IH0  131072     // 64 tiles, KB=4
#define OFF_HH0  262144     // 64 tiles, KB=8
#define OFF_IH1  524288     // 64 tiles, KB=8
#define OFF_HH1  786432     // 64 tiles, KB=8
#define OFF_OUT  1048576    // 4 tiles,  KB=8

// payload boxes: 2KB x 256 blocks x 2 kinds x 2 slots = 2MB (R16 layout)
#define COMM_B   2228224
#define OBOX(bid,kind,slot) (COMM_B + ((((bid)*2+(kind))*2+(slot)) << 11))
// per-wave flag quads: 16B per (bid,kind) = 4 u32 (one per producer wave)
#define FLAG_B   (COMM_B + 2097152)
#define FLAGQ(bid,kind) (FLAG_B + (((bid)*2+(kind)) << 4))
#define SPIN_LIMIT (1<<15)
#define HST 264

__device__ __forceinline__ u16 f2bf(float x){
  unsigned u = __builtin_bit_cast(unsigned, x);
  return (u16)((u + 0x7fffu + ((u >> 16) & 1u)) >> 16);  // RNE
}

__global__ __launch_bounds__(256) void convert_swizzle(
    const float* __restrict__ src, u16* __restrict__ dst,
    int ntiles, int kbshift)
{
  int idx = blockIdx.x * 256 + threadIdx.x;
  int kblocks = 1 << kbshift;
  int n = ntiles << (kbshift + 9);
  if (idx >= n) return;
  int j    = idx & 7;
  int lane = (idx >> 3) & 63;
  int t3   = idx >> 9;
  int kt   = t3 & (kblocks - 1);
  int nt   = t3 >> kbshift;
  int row  = nt * 16 + (lane & 15);
  int k    = kt * 32 + (lane >> 4) * 8 + j;
  dst[idx] = f2bf(src[row * (kblocks * 32) + k]);
}

__device__ __forceinline__ f32x4 mfma16(bf16x8 a, bf16x8 b, f32x4 c){
  return __builtin_amdgcn_mfma_f32_16x16x32_bf16(a, b, c, 0, 0, 0);
}
__device__ __forceinline__ bf16x8 ld8(const u16* p){ return *(const bf16x8*)p; }
__device__ __forceinline__ float sigm(float x){ return 1.f/(1.f + __expf(-x)); }
__device__ __forceinline__ float tanh_f(float x){ return 1.f - 2.f/(__expf(2.f*x) + 1.f); }

#define ISSUE4(Q, seg, kt) \
  asm volatile( \
    "global_load_dwordx4 %0, %4, %8\n\t" \
    "global_load_dwordx4 %1, %5, %8\n\t" \
    "global_load_dwordx4 %2, %6, %8\n\t" \
    "global_load_dwordx4 %3, %7, %8" \
    : "=&v"(Q[0]), "=&v"(Q[1]), "=&v"(Q[2]), "=&v"(Q[3]) \
    : "v"(voffW +           (u32)((kt)*1024)), \
      "v"(voffW + 131072u + (u32)((kt)*1024)), \
      "v"(voffW + 262144u + (u32)((kt)*1024)), \
      "v"(voffW + 393216u + (u32)((kt)*1024)), \
      "s"(seg) \
    : "memory")

#define WAITN(Q, lit) \
  asm volatile("s_waitcnt vmcnt(" lit ")" \
    : "+v"(Q[0]), "+v"(Q[1]), "+v"(Q[2]), "+v"(Q[3]) :: "memory")
#define WAITC(Q) WAITN(Q, "12")

#define MFMA4(afrag, Q) { \
  acc0 = mfma16(afrag, Q[0], acc0); \
  acc1 = mfma16(afrag, Q[1], acc1); \
  acc2 = mfma16(afrag, Q[2], acc2); \
  acc3 = mfma16(afrag, Q[3], acc3); }

#define BARX() asm volatile("s_waitcnt lgkmcnt(0)\n\ts_barrier" ::: "memory")
#define VDRAIN() asm volatile("s_waitcnt vmcnt(0)" ::: "memory")

__device__ __forceinline__ void stflag(u32* p, u32 v){
  __hip_atomic_store(p, v, __ATOMIC_RELAXED, __HIP_MEMORY_SCOPE_AGENT);
}
__device__ __forceinline__ void pub16(char* p, u32 v){
  asm volatile("global_store_short %0, %1, off sc0 sc1" :: "v"(p), "v"(v) : "memory");
}

// poll partner flag-quads (4 wave-flags each, one dwordx4/partner), then
// load + scatter payloads (R16-proven shapes). Wave's vm queue may hold
// prefetched weight loads; the vmcnt(0) here drains them (they land in
// their tied registers -> harmless, data arrives during G anyway).
__device__ __forceinline__ void gatherF(u16* hdst,
    const char* pay0, const char* pay1,
    const char* fq0, const char* fq1, int pcnt,
    int ps0, int ps1, int lane, u32 tgt, int* dead)
{
  if (!*dead){
    int gc = 0;
    for(;;){
      u32x4 fa, fb;
      asm volatile(
        "global_load_dwordx4 %0, %2, off sc0 sc1\n\t"
        "global_load_dwordx4 %1, %3, off sc0 sc1\n\t"
        "s_waitcnt vmcnt(0)"
        : "=&v"(fa), "=&v"(fb)
        : "v"(fq0), "v"(fq1)
        : "memory");
      bool ok = (fa[0] >= tgt) & (fa[1] >= tgt) & (fa[2] >= tgt) & (fa[3] >= tgt);
      if (pcnt == 2)
        ok = ok & (fb[0] >= tgt) & (fb[1] >= tgt) & (fb[2] >= tgt) & (fb[3] >= tgt);
      if (ok) break;
      if (++gc > SPIN_LIMIT){ *dead = 1; break; }
    }
  }
  int base = (lane >> 1)*HST + (lane & 1)*16;
  u32x4 q0, q1, q2, q3;
  if (pcnt == 2){
    asm volatile(
      "global_load_dwordx4 %0, %4, off sc0 sc1\n\t"
      "global_load_dwordx4 %1, %5, off sc0 sc1\n\t"
      "global_load_dwordx4 %2, %6, off sc0 sc1\n\t"
      "global_load_dwordx4 %3, %7, off sc0 sc1"
      : "=&v"(q0), "=&v"(q1), "=&v"(q2), "=&v"(q3)
      : "v"(pay0), "v"(pay0+16), "v"(pay1), "v"(pay1+16)
      : "memory");
    asm volatile("s_waitcnt vmcnt(0)"
      : "+v"(q0), "+v"(q1), "+v"(q2), "+v"(q3) :: "memory");
    *(u32x4*)&hdst[base + ps0*32]     = q0;
    *(u32x4*)&hdst[base + ps0*32 + 8] = q1;
    *(u32x4*)&hdst[base + ps1*32]     = q2;
    *(u32x4*)&hdst[base + ps1*32 + 8] = q3;
  } else {
    asm volatile(
      "global_load_dwordx4 %0, %2, off sc0 sc1\n\t"
      "global_load_dwordx4 %1, %3, off sc0 sc1"
      : "=&v"(q0), "=&v"(q1)
      : "v"(pay0), "v"(pay0+16)
      : "memory");
    asm volatile("s_waitcnt vmcnt(0)" : "+v"(q0), "+v"(q1) :: "memory");
    *(u32x4*)&hdst[base + ps0*32]     = q0;
    *(u32x4*)&hdst[base + ps0*32 + 8] = q1;
  }
}

__global__ __launch_bounds__(512)
void lstm_fused(
    const float* __restrict__ latent,
    const float* __restrict__ b_lh, const float* __restrict__ b_lc,
    const float* __restrict__ b_ih0, const float* __restrict__ b_hh0,
    const float* __restrict__ b_ih1, const float* __restrict__ b_hh1,
    const float* __restrict__ b_out,
    const u16* __restrict__ ws,
    u16* __restrict__ comm,
    float* __restrict__ out)
{
  __shared__ __attribute__((aligned(16))) u16 h0f[2][32*HST];   // 33.8KB
  __shared__ __attribute__((aligned(16))) u16 h1f[3][32*HST];   // 50.7KB (ring)
  __shared__ __attribute__((aligned(16))) u16 hh1L[64*512];     // 64KB
  __shared__ __attribute__((aligned(16))) u16 lat_s[32*136];    // 8.5KB

  const u16* __restrict__ w_lh  = ws + OFF_LH;
  const u16* __restrict__ w_lc  = ws + OFF_LC;
  const u16* __restrict__ w_ih0 = ws + OFF_IH0;
  const u16* __restrict__ w_hh0 = ws + OFF_HH0;
  const u16* __restrict__ w_ih1 = ws + OFF_IH1;
  const u16* __restrict__ w_hh1 = ws + OFF_HH1;
  const u16* __restrict__ w_out = ws + OFF_OUT;

  const int tid  = threadIdx.x;
  const int w    = tid >> 6;          // wave 0..7
  const int lane = tid & 63;
  const int col  = lane & 15;
  const int quad = lane >> 4;
  const int bid  = blockIdx.x;        // 0..255
  const int s    = bid & 7;           // column slice
  const int g    = bid >> 3;          // batch group (32 rows)
  const int rt   = w & 1;
  const int hct  = (w >> 1) & 1;
  const int hrow = quad * 4;
  const int l8   = lane * 8;
  const int ctb  = (s*2 + hct) * 16;
  const u32 voffW = (u32)((s*2 + hct) * 8192 + lane * 16);
  const int hreadR = (rt*16 + col) * HST + quad * 8;
  char* cm = (char*)comm;

  // ---- stage latent (bf16) ----
  for (int i = tid; i < 32*128; i += 512){
    int b = i >> 7, k = i & 127;
    lat_s[b*136 + k] = f2bf(latent[(g*32 + b)*128 + k]);
  }
  __syncthreads();

  // ---- prologue: h(-1) full (local) ----
  #pragma unroll 1
  for (int i = 0; i < 8; ++i){
    int task = w*8 + i;
    int layer = task >> 5, rem = task & 31, rtq = rem >> 4, ct = rem & 15;
    int nt = layer*16 + ct;
    float bias = b_lh[nt*16 + col];
    f32x4 a = {bias, bias, bias, bias};
    #pragma unroll
    for (int kt = 0; kt < 4; ++kt){
      bf16x8 la = ld8(&lat_s[(rtq*16 + col)*136 + kt*32 + quad*8]);
      a = mfma16(la, ld8(w_lh + ((nt*4 + kt) << 9) + l8), a);
    }
    u16* dst = layer ? h1f[2] : h0f[1];   // h1(-1) -> ring slot 2
    #pragma unroll
    for (int rr = 0; rr < 4; ++rr)
      dst[(rtq*16 + hrow + rr)*HST + ct*16 + col] = f2bf(a[rr]);
  }

  // hh1 slice -> LDS
  for (int i = tid; i < 4096; i += 512){
    int f = i >> 6, l = i & 63;
    int gate = f >> 4, hctf = (f >> 3) & 1, kt = f & 7;
    int nt = gate*16 + s*2 + hctf;
    *(bf16x8*)&hh1L[i*8] = ld8(w_hh1 + ((nt*8 + kt) << 9) + l*8);
  }

  bf16x8 latA[4];
  #pragma unroll
  for (int kt = 0; kt < 4; ++kt)
    latA[kt] = ld8(&lat_s[(rt*16 + col)*136 + kt*32 + quad*8]);

  f32x4 gx0[4] = {};
  float bias1[4] = {};
  float c0[4] = {}, c1[4] = {};
  const float bo = (w < 2 && s < 4) ? b_out[s*16 + col] : 0.f;

  if (w < 4){
    { float bias = b_lc[ctb + col]; f32x4 a = {bias,bias,bias,bias};
      #pragma unroll
      for (int kt = 0; kt < 4; ++kt)
        a = mfma16(latA[kt], ld8(w_lc + (((s*2+hct)*4 + kt) << 9) + l8), a);
      #pragma unroll
      for (int rr = 0; rr < 4; ++rr) c0[rr] = a[rr]; }
    #pragma unroll
    for (int g_ = 0; g_ < 4; ++g_){
      int nt = g_*16 + s*2 + hct;
      float bias = b_ih0[nt*16 + col] + b_hh0[nt*16 + col];
      f32x4 a = {bias, bias, bias, bias};
      #pragma unroll
      for (int kt = 0; kt < 4; ++kt)
        a = mfma16(latA[kt], ld8(w_ih0 + ((nt*4 + kt) << 9) + l8), a);
      gx0[g_] = a;
    }
  } else {
    { float bias = b_lc[256 + ctb + col]; f32x4 a = {bias,bias,bias,bias};
      #pragma unroll
      for (int kt = 0; kt < 4; ++kt)
        a = mfma16(latA[kt], ld8(w_lc + (((16 + s*2+hct)*4 + kt) << 9) + l8), a);
      #pragma unroll
      for (int rr = 0; rr < 4; ++rr) c1[rr] = a[rr]; }
    #pragma unroll
    for (int g_ = 0; g_ < 4; ++g_){
      int nt = g_*16 + s*2 + hct;
      bias1[g_] = b_ih1[nt*16 + col] + b_hh1[nt*16 + col];
    }
  }

  // partner/payload/flag addressing (partner bid = g*8 + ps)
  const int wl = w & 3;
  const int pcnt = (wl < 3) ? 2 : 1;
  int i0 = wl*2, i1 = wl*2 + 1;
  int ps0 = (i0 < s) ? i0 : i0 + 1;
  int ps1 = (i1 < s) ? i1 : i1 + 1;
  if (pcnt == 1) ps1 = ps0;
  const int kindm = (w < 4) ? 0 : 1;
  const char* ppay0 = cm + OBOX(g*8 + ps0, kindm, 0) + lane*32;
  const char* ppay1 = cm + OBOX(g*8 + ps1, kindm, 0) + lane*32;
  const char* fq0 = cm + FLAGQ(g*8 + ps0, kindm);
  const char* fq1 = cm + FLAGQ(g*8 + ps1, kindm);
  u32* fmyw = (u32*)(cm + FLAGQ(bid, kindm)) + wl;
  char* pub_own = cm + OBOX(bid, kindm, 0)
                + (((rt*16 + hrow)*32 + hct*16 + col) << 1);
  int dead = 0;

  __syncthreads();

  // ---- prologue X': gates(0) -> nonlin -> h0(0) own + pub + flag (w0-3) ----
  bf16x8 Pq0[4], Pq1[4], Pq2[4], Pq3[4];
  f32x4 acc0, acc1, acc2, acc3;
  bf16x8 a0;
  if (w < 4){
    ISSUE4(Pq0, w_hh0, 0); ISSUE4(Pq1, w_hh0, 1);
    ISSUE4(Pq2, w_hh0, 2); ISSUE4(Pq3, w_hh0, 3);
    const u16* h0m1 = h0f[1];
    acc0 = gx0[0]; acc1 = gx0[1]; acc2 = gx0[2]; acc3 = gx0[3];
    WAITC(Pq0);      a0 = ld8(&h0m1[hreadR + 0*32]); MFMA4(a0, Pq0); ISSUE4(Pq0, w_hh0, 4);
    WAITC(Pq1);      a0 = ld8(&h0m1[hreadR + 1*32]); MFMA4(a0, Pq1); ISSUE4(Pq1, w_hh0, 5);
    WAITC(Pq2);      a0 = ld8(&h0m1[hreadR + 2*32]); MFMA4(a0, Pq2); ISSUE4(Pq2, w_hh0, 6);
    WAITC(Pq3);      a0 = ld8(&h0m1[hreadR + 3*32]); MFMA4(a0, Pq3); ISSUE4(Pq3, w_hh0, 7);
    WAITC(Pq0);      a0 = ld8(&h0m1[hreadR + 4*32]); MFMA4(a0, Pq0);
    WAITN(Pq1, "8"); a0 = ld8(&h0m1[hreadR + 5*32]); MFMA4(a0, Pq1);
    WAITN(Pq2, "4"); a0 = ld8(&h0m1[hreadR + 6*32]); MFMA4(a0, Pq2);
    WAITN(Pq3, "0"); a0 = ld8(&h0m1[hreadR + 7*32]); MFMA4(a0, Pq3);
    #pragma unroll
    for (int rr = 0; rr < 4; ++rr){
      float ii = sigm(acc0[rr]);
      float ff = sigm(acc1[rr]);
      float gg = tanh_f(acc2[rr]);
      float oo = sigm(acc3[rr]);
      float c = ff*c0[rr] + ii*gg;
      c0[rr] = c;
      u16 hb = f2bf(oo * tanh_f(c));
      h0f[0][(rt*16 + hrow + rr)*HST + ctb + col] = hb;   // h0(0), slot 0
      pub16(pub_own + rr*64, (u32)hb);                     // pub slot 0
    }
    VDRAIN();
    __builtin_amdgcn_sched_barrier(0);
    if (lane == 0) stflag(fmyw, 1u);     // h0(0) published
    ISSUE4(Pq0, w_hh0, 0); ISSUE4(Pq1, w_hh0, 1);
    ISSUE4(Pq2, w_hh0, 2); ISSUE4(Pq3, w_hh0, 3);
  } else {
    ISSUE4(Pq0, w_ih1, 0); ISSUE4(Pq1, w_ih1, 1);
    ISSUE4(Pq2, w_ih1, 2); ISSUE4(Pq3, w_ih1, 3);
  }

  int m0 = 0, m1 = 2, m2 = 1;   // h1 ring: h1(t)=m0, h1(t-1)=m1, h1(t-2)=m2

  for (int t = 0; t < 256; ++t){
    const int p = t & 1;
    u16* h0c  = h0f[p];        // h0(t)
    u16* h0n  = h0f[p ^ 1];    // h0(t+1) target
    u16* h1c  = h1f[m0];       // h1(t) target
    u16* h1pr = h1f[m1];       // h1(t-1)

    // ======== phase G ========
    if (w < 4){
      gatherF(h0c, ppay0 + (p << 11), ppay1 + (p << 11),
              fq0, fq1, pcnt, ps0, ps1, lane, (u32)(t+1), &dead);
    } else if (t > 0){
      gatherF(h1pr, ppay0 + ((p^1) << 11), ppay1 + ((p^1) << 11),
              fq0, fq1, pcnt, ps0, ps1, lane, (u32)t, &dead);
    }
    BARX();   // bar1: h0(t) and h1(t-1) full in LDS

    // ======== phase X ========
    if (w < 4){
      // gates(t+1) = gx0 + w_hh0 * h0(t) -> nonlin -> h0(t+1) own + pub
      acc0 = gx0[0]; acc1 = gx0[1]; acc2 = gx0[2]; acc3 = gx0[3];
      WAITC(Pq0);      a0 = ld8(&h0c[hreadR + 0*32]); MFMA4(a0, Pq0); ISSUE4(Pq0, w_hh0, 4);
      WAITC(Pq1);      a0 = ld8(&h0c[hreadR + 1*32]); MFMA4(a0, Pq1); ISSUE4(Pq1, w_hh0, 5);
      WAITC(Pq2);      a0 = ld8(&h0c[hreadR + 2*32]); MFMA4(a0, Pq2); ISSUE4(Pq2, w_hh0, 6);
      WAITC(Pq3);      a0 = ld8(&h0c[hreadR + 3*32]); MFMA4(a0, Pq3); ISSUE4(Pq3, w_hh0, 7);
      WAITC(Pq0);      a0 = ld8(&h0c[hreadR + 4*32]); MFMA4(a0, Pq0);
      WAITN(Pq1, "8"); a0 = ld8(&h0c[hreadR + 5*32]); MFMA4(a0, Pq1);
      WAITN(Pq2, "4"); a0 = ld8(&h0c[hreadR + 6*32]); MFMA4(a0, Pq2);
      WAITN(Pq3, "0"); a0 = ld8(&h0c[hreadR + 7*32]); MFMA4(a0, Pq3);
      #pragma unroll
      for (int rr = 0; rr < 4; ++rr){
        float ii = sigm(acc0[rr]);
        float ff = sigm(acc1[rr]);
        float gg = tanh_f(acc2[rr]);
        float oo = sigm(acc3[rr]);
        float c = ff*c0[rr] + ii*gg;
        c0[rr] = c;
        u16 hb = f2bf(oo * tanh_f(c));
        h0n[(rt*16 + hrow + rr)*HST + ctb + col] = hb;     // h0(t+1)
        pub16(pub_own + ((p^1) << 11) + rr*64, (u32)hb);   // pub slot p^1
      }
      VDRAIN();  // only 4 pub stores outstanding
      __builtin_amdgcn_sched_barrier(0);
      if (lane == 0) stflag(fmyw, (u32)(t+2));             // h0(t+1) published
      ISSUE4(Pq0, w_hh0, 0); ISSUE4(Pq1, w_hh0, 1);        // next step
      ISSUE4(Pq2, w_hh0, 2); ISSUE4(Pq3, w_hh0, 3);
      if (w < 2 && s < 4 && t >= 2){
        // out-proj(t-2): tile s, rows rt=w; h1f[m2] untouched this phase
        const u16* h1o = h1f[m2];
        f32x4 o = {bo, bo, bo, bo};
        #pragma unroll
        for (int kt = 0; kt < 8; ++kt){
          bf16x8 af = ld8(&h1o[hreadR + kt*32]);
          o = mfma16(af, ld8(w_out + ((s*8 + kt) << 9) + l8), o);
        }
        #pragma unroll
        for (int rr = 0; rr < 4; ++rr){
          int b = g*32 + rt*16 + hrow + rr;
          __builtin_nontemporal_store(o[rr], &out[(b*256 + (t-2))*64 + s*16 + col]);
        }
      }
    } else {
      // hh1 from LDS-resident w_hh1 over full h1(t-1)
      acc0 = (f32x4){bias1[0],bias1[0],bias1[0],bias1[0]};
      acc1 = (f32x4){bias1[1],bias1[1],bias1[1],bias1[1]};
      acc2 = (f32x4){bias1[2],bias1[2],bias1[2],bias1[2]};
      acc3 = (f32x4){bias1[3],bias1[3],bias1[3],bias1[3]};
      #pragma unroll
      for (int kt = 0; kt < 8; ++kt){
        bf16x8 af = ld8(&h1pr[hreadR + kt*32]);
        acc0 = mfma16(af, ld8(&hh1L[((0*2 + hct)*8 + kt)*512 + l8]), acc0);
        acc1 = mfma16(af, ld8(&hh1L[((1*2 + hct)*8 + kt)*512 + l8]), acc1);
        acc2 = mfma16(af, ld8(&hh1L[((2*2 + hct)*8 + kt)*512 + l8]), acc2);
        acc3 = mfma16(af, ld8(&hh1L[((3*2 + hct)*8 + kt)*512 + l8]), acc3);
      }
      // ih1 over full h0(t); decreasing tail so VDRAIN sees only pub stores
      WAITC(Pq0);      a0 = ld8(&h0c[hreadR + 0*32]); MFMA4(a0, Pq0); ISSUE4(Pq0, w_ih1, 4);
      WAITC(Pq1);      a0 = ld8(&h0c[hreadR + 1*32]); MFMA4(a0, Pq1); ISSUE4(Pq1, w_ih1, 5);
      WAITC(Pq2);      a0 = ld8(&h0c[hreadR + 2*32]); MFMA4(a0, Pq2); ISSUE4(Pq2, w_ih1, 6);
      WAITC(Pq3);      a0 = ld8(&h0c[hreadR + 3*32]); MFMA4(a0, Pq3); ISSUE4(Pq3, w_ih1, 7);
      WAITC(Pq0);      a0 = ld8(&h0c[hreadR + 4*32]); MFMA4(a0, Pq0);
      WAITN(Pq1, "8"); a0 = ld8(&h0c[hreadR + 5*32]); MFMA4(a0, Pq1);
      WAITN(Pq2, "4"); a0 = ld8(&h0c[hreadR + 6*32]); MFMA4(a0, Pq2);
      WAITN(Pq3, "0"); a0 = ld8(&h0c[hreadR + 7*32]); MFMA4(a0, Pq3);
      #pragma unroll
      for (int rr = 0; rr < 4; ++rr){
        float ii = sigm(acc0[rr]);
        float ff = sigm(acc1[rr]);
        float gg = tanh_f(acc2[rr]);
        float oo = sigm(acc3[rr]);
        float c = ff*c1[rr] + ii*gg;
        c1[rr] = c;
        u16 hb = f2bf(oo * tanh_f(c));
        h1c[(rt*16 + hrow + rr)*HST + ctb + col] = hb;     // h1(t)
        pub16(pub_own + (p << 11) + rr*64, (u32)hb);       // pub slot p
      }
      VDRAIN();  // only 4 pub stores outstanding
      __builtin_amdgcn_sched_barrier(0);
      if (lane == 0) stflag(fmyw, (u32)(t+1));             // h1(t) published
      ISSUE4(Pq0, w_ih1, 0); ISSUE4(Pq1, w_ih1, 1);        // next step
      ISSUE4(Pq2, w_ih1, 2); ISSUE4(Pq3, w_ih1, 3);
    }
    BARX();   // bar2: h0(t+1) own + h1(t) own tiles in LDS

    int tm = m2; m2 = m1; m1 = m0; m0 = tm;   // rotate h1 ring
  }

  // ---- epilogue: gather h1(255) into slot 0; out(254) from slot 2; out(255) ----
  if (w >= 4){
    gatherF(h1f[0], ppay0 + (1 << 11), ppay1 + (1 << 11),
            fq0, fq1, pcnt, ps0, ps1, lane, 256u, &dead);
  } else if (w < 2 && s < 4){
    const u16* h1o = h1f[2];   // h1(254)
    f32x4 o = {bo, bo, bo, bo};
    #pragma unroll
    for (int kt = 0; kt < 8; ++kt){
      bf16x8 af = ld8(&h1o[hreadR + kt*32]);
      o = mfma16(af, ld8(w_out + ((s*8 + kt) << 9) + l8), o);
    }
    #pragma unroll
    for (int rr = 0; rr < 4; ++rr){
      int b = g*32 + rt*16 + hrow + rr;
      __builtin_nontemporal_store(o[rr], &out[(b*256 + 254)*64 + s*16 + col]);
    }
  }
  BARX();
  if (w < 2 && s < 4){
    const u16* h1fin = h1f[0];  // h1(255)
    f32x4 o = {bo, bo, bo, bo};
    #pragma unroll
    for (int kt = 0; kt < 8; ++kt){
      bf16x8 af = ld8(&h1fin[hreadR + kt*32]);
      o = mfma16(af, ld8(w_out + ((s*8 + kt) << 9) + l8), o);
    }
    #pragma unroll
    for (int rr = 0; rr < 4; ++rr){
      int b = g*32 + rt*16 + hrow + rr;
      __builtin_nontemporal_store(o[rr], &out[(b*256 + 255)*64 + s*16 + col]);
    }
  }
}

extern "C" void kernel_launch(void* const* d_in, const int* in_sizes, int n_in,
                              void* d_out, int out_size, void* d_ws, size_t ws_size,
                              hipStream_t stream)
{
  (void)in_sizes; (void)n_in; (void)out_size; (void)ws_size;
  const float* latent = (const float*)d_in[0];
  const float* w_lh   = (const float*)d_in[1];
  const float* b_lh   = (const float*)d_in[2];
  const float* w_lc   = (const float*)d_in[3];
  const float* b_lc   = (const float*)d_in[4];
  const float* w_ih0  = (const float*)d_in[5];
  const float* w_hh0  = (const float*)d_in[6];
  const float* b_ih0  = (const float*)d_in[7];
  const float* b_hh0  = (const float*)d_in[8];
  const float* w_ih1  = (const float*)d_in[9];
  const float* w_hh1  = (const float*)d_in[10];
  const float* b_ih1  = (const float*)d_in[11];
  const float* b_hh1  = (const float*)d_in[12];
  const float* w_out  = (const float*)d_in[13];
  const float* b_out  = (const float*)d_in[14];
  u16* ws = (u16*)d_ws;
  float* out = (float*)d_out;

  auto cvt = [&](const float* src, int off, int ntiles, int kbshift){
    int n = ntiles << (kbshift + 9);
    convert_swizzle<<<dim3((n + 255)/256), dim3(256), 0, stream>>>(src, ws + off, ntiles, kbshift);
  };
  cvt(w_lh,  OFF_LH,  32, 2);
  cvt(w_lc,  OFF_LC,  32, 2);
  cvt(w_ih0, OFF_IH0, 64, 2);
  cvt(w_hh0, OFF_HH0, 64, 3);
  cvt(w_ih1, OFF_IH1, 64, 3);
  cvt(w_hh1, OFF_HH1, 64, 3);
  cvt(w_out, OFF_OUT, 4, 3);

  // reset per-wave flag quads (captured graph node; monotonic from 0 each replay)
  hipMemsetAsync((char*)d_ws + FLAG_B, 0, 256*2*16, stream);

  lstm_fused<<<dim3(256), dim3(512), 0, stream>>>(latent, b_lh, b_lc, b_ih0, b_hh0,
                                                  b_ih1, b_hh1, b_out, ws, ws, out);
}

// Round 9
// 1454.443 us; speedup vs baseline: 1.6421x; 1.0013x over previous
//
#include <hip/hip_runtime.h>

// LSTMDecoder: B=1024, L=128, H=256, OUT=64, T=256, 2 layers.
// R19: repartition 32x8 -> 64x4 (16 rows x 64 cols per block) + coalesced
// 8B record publishes. Evidence: FETCH ~930MB invariant across R14/R16/R18
// = the sc0/sc1 gather traffic itself; (FETCH+WRITE)/dur = 917GB/s =
// hbm_gbps exactly -> exchange-path bound. C=4 cuts gathered bytes
// 28KB->12KB/block/step (3 partners, not 7; skew = max of 3), pubs become
// one global_store_dwordx2 per thread (4x fewer write transactions,
// wave-contiguous 512B regions). hh1 leaves LDS (was 64KB + ~2k cyc/step
// of ds_read) and joins the proven inline-asm stream: w4-7 runs a
// 16-chunk hh1(k0-7)->ih1(k0-7) rotation, uniform vmcnt(12), wrapping
// into next step's hh1 k0-3. Streams: w0-3 hh0 128KB, w4-7 hh1+ih1 256KB
// (384KB/step/CU; 12MB/step/XCD ~ 2.8us of L2 BW). out-proj balanced:
// every block owns OUT tile s on wave 0. Everything else = R18 verbatim:
// 2-phase step {G,bar,X,bar}, per-wave flags posted pre-barrier after a
// 1-store VDRAIN, 2-slot payload boxes with the same transitive reuse
// proof, 3-deep h1 ring for out-proj(t-2), bounded spin-guard.

typedef float f32x4 __attribute__((ext_vector_type(4)));
typedef short bf16x8 __attribute__((ext_vector_type(8)));
typedef unsigned short u16;
typedef unsigned int u32;
typedef unsigned int u32x2 __attribute__((ext_vector_type(2)));
typedef unsigned int u32x4 __attribute__((ext_vector_type(4)));

#define OFF_LH   0          // 32 tiles, KB=4
#define OFF_LC   65536      // 32 tiles, KB=4
#define OFF_IH0  131072     // 64 tiles, KB=4
#define OFF_HH0  262144     // 64 tiles, KB=8
#define OFF_IH1  524288     // 64 tiles, KB=8
#define OFF_HH1  786432     // 64 tiles, KB=8
#define OFF_OUT  1048576    // 4 tiles,  KB=8

// payload boxes: 2KB x 256 blocks x 2 kinds x 2 slots = 2MB
#define COMM_B   2228224
#define OBOX(bid,kind,slot) (COMM_B + ((((bid)*2+(kind))*2+(slot)) << 11))
// per-wave flag quads: 16B per (bid,kind)
#define FLAG_B   (COMM_B + 2097152)
#define FLAGQ(bid,kind) (FLAG_B + (((bid)*2+(kind)) << 4))
#define SPIN_LIMIT (1<<15)
#define HST 264

__device__ __forceinline__ u16 f2bf(float x){
  unsigned u = __builtin_bit_cast(unsigned, x);
  return (u16)((u + 0x7fffu + ((u >> 16) & 1u)) >> 16);  // RNE
}

__global__ __launch_bounds__(256) void convert_swizzle(
    const float* __restrict__ src, u16* __restrict__ dst,
    int ntiles, int kbshift)
{
  int idx = blockIdx.x * 256 + threadIdx.x;
  int kblocks = 1 << kbshift;
  int n = ntiles << (kbshift + 9);
  if (idx >= n) return;
  int j    = idx & 7;
  int lane = (idx >> 3) & 63;
  int t3   = idx >> 9;
  int kt   = t3 & (kblocks - 1);
  int nt   = t3 >> kbshift;
  int row  = nt * 16 + (lane & 15);
  int k    = kt * 32 + (lane >> 4) * 8 + j;
  dst[idx] = f2bf(src[row * (kblocks * 32) + k]);
}

__device__ __forceinline__ f32x4 mfma16(bf16x8 a, bf16x8 b, f32x4 c){
  return __builtin_amdgcn_mfma_f32_16x16x32_bf16(a, b, c, 0, 0, 0);
}
__device__ __forceinline__ bf16x8 ld8(const u16* p){ return *(const bf16x8*)p; }
__device__ __forceinline__ float sigm(float x){ return 1.f/(1.f + __expf(-x)); }
__device__ __forceinline__ float tanh_f(float x){ return 1.f - 2.f/(__expf(2.f*x) + 1.f); }

#define ISSUE4(Q, seg, kt) \
  asm volatile( \
    "global_load_dwordx4 %0, %4, %8\n\t" \
    "global_load_dwordx4 %1, %5, %8\n\t" \
    "global_load_dwordx4 %2, %6, %8\n\t" \
    "global_load_dwordx4 %3, %7, %8" \
    : "=&v"(Q[0]), "=&v"(Q[1]), "=&v"(Q[2]), "=&v"(Q[3]) \
    : "v"(voffW +           (u32)((kt)*1024)), \
      "v"(voffW + 131072u + (u32)((kt)*1024)), \
      "v"(voffW + 262144u + (u32)((kt)*1024)), \
      "v"(voffW + 393216u + (u32)((kt)*1024)), \
      "s"(seg) \
    : "memory")

#define WAITN(Q, lit) \
  asm volatile("s_waitcnt vmcnt(" lit ")" \
    : "+v"(Q[0]), "+v"(Q[1]), "+v"(Q[2]), "+v"(Q[3]) :: "memory")
#define WAITC(Q) WAITN(Q, "12")

#define MFMA4(afrag, Q) { \
  acc0 = mfma16(afrag, Q[0], acc0); \
  acc1 = mfma16(afrag, Q[1], acc1); \
  acc2 = mfma16(afrag, Q[2], acc2); \
  acc3 = mfma16(afrag, Q[3], acc3); }

#define BARX() asm volatile("s_waitcnt lgkmcnt(0)\n\ts_barrier" ::: "memory")
#define VDRAIN() asm volatile("s_waitcnt vmcnt(0)" ::: "memory")

__device__ __forceinline__ void stflag(u32* p, u32 v){
  __hip_atomic_store(p, v, __ATOMIC_RELAXED, __HIP_MEMORY_SCOPE_AGENT);
}
// coalesced 8B record: {rows hrow+0,+1 | rows hrow+2,+3} for one col
__device__ __forceinline__ void pub8(char* p, u32 lo, u32 hi){
  u32x2 v = {lo, hi};
  asm volatile("global_store_dwordx2 %0, %1, off sc0 sc1" :: "v"(p), "v"(v) : "memory");
}

// gather ONE partner box (2KB, 4 x 512B wave-regions of 8B col-records):
// poll its 4 wave-flags (one dwordx4), then 32B/lane payload, scatter.
__device__ __forceinline__ void gatherF1(u16* hdst,
    const char* pay, const char* fq, int ps, int lane, u32 tgt, int* dead)
{
  if (!*dead){
    int gc = 0;
    for(;;){
      u32x4 fa;
      asm volatile(
        "global_load_dwordx4 %0, %1, off sc0 sc1\n\ts_waitcnt vmcnt(0)"
        : "=&v"(fa) : "v"(fq) : "memory");
      if (fa[0] >= tgt && fa[1] >= tgt && fa[2] >= tgt && fa[3] >= tgt) break;
      if (++gc > SPIN_LIMIT){ *dead = 1; break; }
    }
  }
  u32x4 q0, q1;
  asm volatile(
    "global_load_dwordx4 %0, %2, off sc0 sc1\n\t"
    "global_load_dwordx4 %1, %3, off sc0 sc1"
    : "=&v"(q0), "=&v"(q1)
    : "v"(pay), "v"(pay+16)
    : "memory");
  asm volatile("s_waitcnt vmcnt(0)" : "+v"(q0), "+v"(q1) :: "memory");
  const int r  = lane >> 4;            // producer wave region (hct4)
  const int cb = ps*64 + r*16;         // col base in full-h LDS
  #pragma unroll
  for (int j = 0; j < 4; ++j){
    u32 lo = (j < 2) ? q0[2*j]   : q1[2*(j-2)];
    u32 hi = (j < 2) ? q0[2*j+1] : q1[2*(j-2)+1];
    int pl = (lane & 15)*4 + j;        // producer lane within region
    u16* dst = &hdst[((pl >> 4)*4)*HST + cb + (pl & 15)];
    dst[0]     = (u16)lo;
    dst[HST]   = (u16)(lo >> 16);
    dst[2*HST] = (u16)hi;
    dst[3*HST] = (u16)(hi >> 16);
  }
}

__global__ __launch_bounds__(512)
void lstm_fused(
    const float* __restrict__ latent,
    const float* __restrict__ b_lh, const float* __restrict__ b_lc,
    const float* __restrict__ b_ih0, const float* __restrict__ b_hh0,
    const float* __restrict__ b_ih1, const float* __restrict__ b_hh1,
    const float* __restrict__ b_out,
    const u16* __restrict__ ws,
    u16* __restrict__ comm,
    float* __restrict__ out)
{
  __shared__ __attribute__((aligned(16))) u16 h0f[2][16*HST];   // 16.9KB
  __shared__ __attribute__((aligned(16))) u16 h1f[3][16*HST];   // 25.3KB (ring)
  __shared__ __attribute__((aligned(16))) u16 lat_s[16*136];    // 4.3KB

  const u16* __restrict__ w_lh  = ws + OFF_LH;
  const u16* __restrict__ w_lc  = ws + OFF_LC;
  const u16* __restrict__ w_ih0 = ws + OFF_IH0;
  const u16* __restrict__ w_hh0 = ws + OFF_HH0;
  const u16* __restrict__ w_ih1 = ws + OFF_IH1;
  const u16* __restrict__ w_hh1 = ws + OFF_HH1;
  const u16* __restrict__ w_out = ws + OFF_OUT;

  const int tid  = threadIdx.x;
  const int w    = tid >> 6;          // wave 0..7
  const int lane = tid & 63;
  const int col  = lane & 15;
  const int quad = lane >> 4;
  const int bid  = blockIdx.x;        // 0..255
  const int s    = bid & 3;           // column slice (64 cols)
  const int g    = bid >> 2;          // batch group (16 rows), 0..63
  const int hct4 = w & 3;             // 16-col subtile within slice
  const int hrow = quad * 4;
  const int l8   = lane * 8;
  const int ctb  = s*64 + hct4*16;    // global h-col base of wave's tile
  const u32 voffW = (u32)((s*4 + hct4) * 8192 + lane * 16);
  const int hreadR = col * HST + quad * 8;   // A-frag read (16 rows)
  char* cm = (char*)comm;

  // ---- stage latent (bf16), 16 rows ----
  for (int i = tid; i < 16*128; i += 512){
    int b = i >> 7, k = i & 127;
    lat_s[b*136 + k] = f2bf(latent[(g*16 + b)*128 + k]);
  }
  __syncthreads();

  // ---- prologue: h(-1) full (local): 32 tile-tasks, 4 per wave ----
  #pragma unroll 1
  for (int i = 0; i < 4; ++i){
    int task = w*4 + i;
    int layer = task >> 4, ct = task & 15;
    int nt = layer*16 + ct;
    float bias = b_lh[nt*16 + col];
    f32x4 a = {bias, bias, bias, bias};
    #pragma unroll
    for (int kt = 0; kt < 4; ++kt){
      bf16x8 la = ld8(&lat_s[col*136 + kt*32 + quad*8]);
      a = mfma16(la, ld8(w_lh + ((nt*4 + kt) << 9) + l8), a);
    }
    u16* dst = layer ? h1f[2] : h0f[1];   // h1(-1) -> ring slot 2
    #pragma unroll
    for (int rr = 0; rr < 4; ++rr)
      dst[(hrow + rr)*HST + ct*16 + col] = f2bf(a[rr]);
  }

  bf16x8 latA[4];
  #pragma unroll
  for (int kt = 0; kt < 4; ++kt)
    latA[kt] = ld8(&lat_s[col*136 + kt*32 + quad*8]);

  f32x4 gx0[4] = {};
  float bias1[4] = {};
  float c0[4] = {}, c1[4] = {};
  const float bo = (w == 0) ? b_out[s*16 + col] : 0.f;

  if (w < 4){
    { float bias = b_lc[ctb + col]; f32x4 a = {bias,bias,bias,bias};
      int nt0 = s*4 + hct4;
      #pragma unroll
      for (int kt = 0; kt < 4; ++kt)
        a = mfma16(latA[kt], ld8(w_lc + ((nt0*4 + kt) << 9) + l8), a);
      #pragma unroll
      for (int rr = 0; rr < 4; ++rr) c0[rr] = a[rr]; }
    #pragma unroll
    for (int g_ = 0; g_ < 4; ++g_){
      int nt = g_*16 + s*4 + hct4;
      float bias = b_ih0[nt*16 + col] + b_hh0[nt*16 + col];
      f32x4 a = {bias, bias, bias, bias};
      #pragma unroll
      for (int kt = 0; kt < 4; ++kt)
        a = mfma16(latA[kt], ld8(w_ih0 + ((nt*4 + kt) << 9) + l8), a);
      gx0[g_] = a;
    }
  } else {
    { float bias = b_lc[256 + ctb + col]; f32x4 a = {bias,bias,bias,bias};
      int nt1 = 16 + s*4 + hct4;
      #pragma unroll
      for (int kt = 0; kt < 4; ++kt)
        a = mfma16(latA[kt], ld8(w_lc + ((nt1*4 + kt) << 9) + l8), a);
      #pragma unroll
      for (int rr = 0; rr < 4; ++rr) c1[rr] = a[rr]; }
    #pragma unroll
    for (int g_ = 0; g_ < 4; ++g_){
      int nt = g_*16 + s*4 + hct4;
      bias1[g_] = b_ih1[nt*16 + col] + b_hh1[nt*16 + col];
    }
  }

  // partner/payload/flag addressing (partner bid = g*4 + ps; 3 partners)
  const int wl = w & 3;
  const int havep = (wl < 3);
  int ps = (wl < s) ? wl : wl + 1;          // {0..3}\{s} for wl=0..2
  if (!havep) ps = 0;
  const int kindm = (w < 4) ? 0 : 1;
  const char* ppay = cm + OBOX(g*4 + ps, kindm, 0) + lane*32;
  const char* fq   = cm + FLAGQ(g*4 + ps, kindm);
  u32* fmyw = (u32*)(cm + FLAGQ(bid, kindm)) + wl;
  char* pub_own = cm + OBOX(bid, kindm, 0) + hct4*512 + lane*8;
  int dead = 0;

  __syncthreads();

  // ---- prologue X': gates(0) -> nonlin -> h0(0) own + pub + flag (w0-3) ----
  bf16x8 Pq0[4], Pq1[4], Pq2[4], Pq3[4];
  f32x4 acc0, acc1, acc2, acc3;
  bf16x8 a0;
  if (w < 4){
    ISSUE4(Pq0, w_hh0, 0); ISSUE4(Pq1, w_hh0, 1);
    ISSUE4(Pq2, w_hh0, 2); ISSUE4(Pq3, w_hh0, 3);
    const u16* h0m1 = h0f[1];
    acc0 = gx0[0]; acc1 = gx0[1]; acc2 = gx0[2]; acc3 = gx0[3];
    WAITC(Pq0);      a0 = ld8(&h0m1[hreadR + 0*32]); MFMA4(a0, Pq0); ISSUE4(Pq0, w_hh0, 4);
    WAITC(Pq1);      a0 = ld8(&h0m1[hreadR + 1*32]); MFMA4(a0, Pq1); ISSUE4(Pq1, w_hh0, 5);
    WAITC(Pq2);      a0 = ld8(&h0m1[hreadR + 2*32]); MFMA4(a0, Pq2); ISSUE4(Pq2, w_hh0, 6);
    WAITC(Pq3);      a0 = ld8(&h0m1[hreadR + 3*32]); MFMA4(a0, Pq3); ISSUE4(Pq3, w_hh0, 7);
    WAITC(Pq0);      a0 = ld8(&h0m1[hreadR + 4*32]); MFMA4(a0, Pq0);
    WAITN(Pq1, "8"); a0 = ld8(&h0m1[hreadR + 5*32]); MFMA4(a0, Pq1);
    WAITN(Pq2, "4"); a0 = ld8(&h0m1[hreadR + 6*32]); MFMA4(a0, Pq2);
    WAITN(Pq3, "0"); a0 = ld8(&h0m1[hreadR + 7*32]); MFMA4(a0, Pq3);
    u32 plo = 0, phi = 0;
    #pragma unroll
    for (int rr = 0; rr < 4; ++rr){
      float ii = sigm(acc0[rr]);
      float ff = sigm(acc1[rr]);
      float gg = tanh_f(acc2[rr]);
      float oo = sigm(acc3[rr]);
      float c = ff*c0[rr] + ii*gg;
      c0[rr] = c;
      u16 hb = f2bf(oo * tanh_f(c));
      h0f[0][(hrow + rr)*HST + ctb + col] = hb;   // h0(0), slot 0
      if (rr & 2) phi |= (u32)hb << ((rr & 1)*16);
      else        plo |= (u32)hb << ((rr & 1)*16);
    }
    pub8(pub_own, plo, phi);                       // pub slot 0
    VDRAIN();
    __builtin_amdgcn_sched_barrier(0);
    if (lane == 0) stflag(fmyw, 1u);
    ISSUE4(Pq0, w_hh0, 0); ISSUE4(Pq1, w_hh0, 1);
    ISSUE4(Pq2, w_hh0, 2); ISSUE4(Pq3, w_hh0, 3);
  } else {
    ISSUE4(Pq0, w_hh1, 0); ISSUE4(Pq1, w_hh1, 1);
    ISSUE4(Pq2, w_hh1, 2); ISSUE4(Pq3, w_hh1, 3);
  }

  int m0 = 0, m1 = 2, m2 = 1;   // h1 ring: h1(t)=m0, h1(t-1)=m1, h1(t-2)=m2

  for (int t = 0; t < 256; ++t){
    const int p = t & 1;
    u16* h0c  = h0f[p];        // h0(t)
    u16* h0n  = h0f[p ^ 1];    // h0(t+1) target
    u16* h1c  = h1f[m0];       // h1(t) target
    u16* h1pr = h1f[m1];       // h1(t-1)

    // ======== phase G ========
    if (w < 4){
      if (havep)
        gatherF1(h0c, ppay + (p << 11), fq, ps, lane, (u32)(t+1), &dead);
    } else if (t > 0 && havep){
      gatherF1(h1pr, ppay + ((p^1) << 11), fq, ps, lane, (u32)t, &dead);
    }
    BARX();   // bar1: h0(t) and h1(t-1) full in LDS

    // ======== phase X ========
    if (w < 4){
      // gates(t+1) = gx0 + w_hh0*h0(t) -> nonlin -> h0(t+1) own + pub
      acc0 = gx0[0]; acc1 = gx0[1]; acc2 = gx0[2]; acc3 = gx0[3];
      WAITC(Pq0);      a0 = ld8(&h0c[hreadR + 0*32]); MFMA4(a0, Pq0); ISSUE4(Pq0, w_hh0, 4);
      WAITC(Pq1);      a0 = ld8(&h0c[hreadR + 1*32]); MFMA4(a0, Pq1); ISSUE4(Pq1, w_hh0, 5);
      WAITC(Pq2);      a0 = ld8(&h0c[hreadR + 2*32]); MFMA4(a0, Pq2); ISSUE4(Pq2, w_hh0, 6);
      WAITC(Pq3);      a0 = ld8(&h0c[hreadR + 3*32]); MFMA4(a0, Pq3); ISSUE4(Pq3, w_hh0, 7);
      WAITC(Pq0);      a0 = ld8(&h0c[hreadR + 4*32]); MFMA4(a0, Pq0);
      WAITN(Pq1, "8"); a0 = ld8(&h0c[hreadR + 5*32]); MFMA4(a0, Pq1);
      WAITN(Pq2, "4"); a0 = ld8(&h0c[hreadR + 6*32]); MFMA4(a0, Pq2);
      WAITN(Pq3, "0"); a0 = ld8(&h0c[hreadR + 7*32]); MFMA4(a0, Pq3);
      u32 plo = 0, phi = 0;
      #pragma unroll
      for (int rr = 0; rr < 4; ++rr){
        float ii = sigm(acc0[rr]);
        float ff = sigm(acc1[rr]);
        float gg = tanh_f(acc2[rr]);
        float oo = sigm(acc3[rr]);
        float c = ff*c0[rr] + ii*gg;
        c0[rr] = c;
        u16 hb = f2bf(oo * tanh_f(c));
        h0n[(hrow + rr)*HST + ctb + col] = hb;     // h0(t+1)
        if (rr & 2) phi |= (u32)hb << ((rr & 1)*16);
        else        plo |= (u32)hb << ((rr & 1)*16);
      }
      pub8(pub_own + ((p^1) << 11), plo, phi);
      VDRAIN();  // 1 pub store
      __builtin_amdgcn_sched_barrier(0);
      if (lane == 0) stflag(fmyw, (u32)(t+2));
      ISSUE4(Pq0, w_hh0, 0); ISSUE4(Pq1, w_hh0, 1);  // next step
      ISSUE4(Pq2, w_hh0, 2); ISSUE4(Pq3, w_hh0, 3);
      if (w == 0 && t >= 2){
        // out-proj(t-2): tile s, all 16 rows; h1f[m2] untouched this phase
        const u16* h1o = h1f[m2];
        f32x4 o = {bo, bo, bo, bo};
        #pragma unroll
        for (int kt = 0; kt < 8; ++kt){
          bf16x8 af = ld8(&h1o[hreadR + kt*32]);
          o = mfma16(af, ld8(w_out + ((s*8 + kt) << 9) + l8), o);
        }
        #pragma unroll
        for (int rr = 0; rr < 4; ++rr){
          int b = g*16 + hrow + rr;
          __builtin_nontemporal_store(o[rr], &out[(b*256 + (t-2))*64 + s*16 + col]);
        }
      }
    } else {
      // bias1 + w_hh1*h1(t-1) + w_ih1*h0(t), 16-chunk streamed rotation
      acc0 = (f32x4){bias1[0],bias1[0],bias1[0],bias1[0]};
      acc1 = (f32x4){bias1[1],bias1[1],bias1[1],bias1[1]};
      acc2 = (f32x4){bias1[2],bias1[2],bias1[2],bias1[2]};
      acc3 = (f32x4){bias1[3],bias1[3],bias1[3],bias1[3]};
      WAITC(Pq0);      a0 = ld8(&h1pr[hreadR + 0*32]); MFMA4(a0, Pq0); ISSUE4(Pq0, w_hh1, 4);
      WAITC(Pq1);      a0 = ld8(&h1pr[hreadR + 1*32]); MFMA4(a0, Pq1); ISSUE4(Pq1, w_hh1, 5);
      WAITC(Pq2);      a0 = ld8(&h1pr[hreadR + 2*32]); MFMA4(a0, Pq2); ISSUE4(Pq2, w_hh1, 6);
      WAITC(Pq3);      a0 = ld8(&h1pr[hreadR + 3*32]); MFMA4(a0, Pq3); ISSUE4(Pq3, w_hh1, 7);
      WAITC(Pq0);      a0 = ld8(&h1pr[hreadR + 4*32]); MFMA4(a0, Pq0); ISSUE4(Pq0, w_ih1, 0);
      WAITC(Pq1);      a0 = ld8(&h1pr[hreadR + 5*32]); MFMA4(a0, Pq1); ISSUE4(Pq1, w_ih1, 1);
      WAITC(Pq2);      a0 = ld8(&h1pr[hreadR + 6*32]); MFMA4(a0, Pq2); ISSUE4(Pq2, w_ih1, 2);
      WAITC(Pq3);      a0 = ld8(&h1pr[hreadR + 7*32]); MFMA4(a0, Pq3); ISSUE4(Pq3, w_ih1, 3);
      WAITC(Pq0);      a0 = ld8(&h0c[hreadR + 0*32]); MFMA4(a0, Pq0); ISSUE4(Pq0, w_ih1, 4);
      WAITC(Pq1);      a0 = ld8(&h0c[hreadR + 1*32]); MFMA4(a0, Pq1); ISSUE4(Pq1, w_ih1, 5);
      WAITC(Pq2);      a0 = ld8(&h0c[hreadR + 2*32]); MFMA4(a0, Pq2); ISSUE4(Pq2, w_ih1, 6);
      WAITC(Pq3);      a0 = ld8(&h0c[hreadR + 3*32]); MFMA4(a0, Pq3); ISSUE4(Pq3, w_ih1, 7);
      WAITC(Pq0);      a0 = ld8(&h0c[hreadR + 4*32]); MFMA4(a0, Pq0);
      WAITN(Pq1, "8"); a0 = ld8(&h0c[hreadR + 5*32]); MFMA4(a0, Pq1);
      WAITN(Pq2, "4"); a0 = ld8(&h0c[hreadR + 6*32]); MFMA4(a0, Pq2);
      WAITN(Pq3, "0"); a0 = ld8(&h0c[hreadR + 7*32]); MFMA4(a0, Pq3);
      u32 plo = 0, phi = 0;
      #pragma unroll
      for (int rr = 0; rr < 4; ++rr){
        float ii = sigm(acc0[rr]);
        float ff = sigm(acc1[rr]);
        float gg = tanh_f(acc2[rr]);
        float oo = sigm(acc3[rr]);
        float c = ff*c1[rr] + ii*gg;
        c1[rr] = c;
        u16 hb = f2bf(oo * tanh_f(c));
        h1c[(hrow + rr)*HST + ctb + col] = hb;     // h1(t)
        if (rr & 2) phi |= (u32)hb << ((rr & 1)*16);
        else        plo |= (u32)hb << ((rr & 1)*16);
      }
      pub8(pub_own + (p << 11), plo, phi);
      VDRAIN();  // 1 pub store
      __builtin_amdgcn_sched_barrier(0);
      if (lane == 0) stflag(fmyw, (u32)(t+1));
      ISSUE4(Pq0, w_hh1, 0); ISSUE4(Pq1, w_hh1, 1);  // next step
      ISSUE4(Pq2, w_hh1, 2); ISSUE4(Pq3, w_hh1, 3);
    }
    BARX();   // bar2: h0(t+1) own + h1(t) own tiles in LDS

    int tm = m2; m2 = m1; m1 = m0; m0 = tm;   // rotate h1 ring
  }

  // ---- epilogue: gather h1(255) into slot 0; out(254) from slot 2; out(255) ----
  if (w >= 4){
    if (havep)
      gatherF1(h1f[0], ppay + (1 << 11), fq, ps, lane, 256u, &dead);
  } else if (w == 0){
    const u16* h1o = h1f[2];   // h1(254)
    f32x4 o = {bo, bo, bo, bo};
    #pragma unroll
    for (int kt = 0; kt < 8; ++kt){
      bf16x8 af = ld8(&h1o[hreadR + kt*32]);
      o = mfma16(af, ld8(w_out + ((s*8 + kt) << 9) + l8), o);
    }
    #pragma unroll
    for (int rr = 0; rr < 4; ++rr){
      int b = g*16 + hrow + rr;
      __builtin_nontemporal_store(o[rr], &out[(b*256 + 254)*64 + s*16 + col]);
    }
  }
  BARX();
  if (w == 0){
    const u16* h1fin = h1f[0];  // h1(255)
    f32x4 o = {bo, bo, bo, bo};
    #pragma unroll
    for (int kt = 0; kt < 8; ++kt){
      bf16x8 af = ld8(&h1fin[hreadR + kt*32]);
      o = mfma16(af, ld8(w_out + ((s*8 + kt) << 9) + l8), o);
    }
    #pragma unroll
    for (int rr = 0; rr < 4; ++rr){
      int b = g*16 + hrow + rr;
      __builtin_nontemporal_store(o[rr], &out[(b*256 + 255)*64 + s*16 + col]);
    }
  }
}

extern "C" void kernel_launch(void* const* d_in, const int* in_sizes, int n_in,
                              void* d_out, int out_size, void* d_ws, size_t ws_size,
                              hipStream_t stream)
{
  (void)in_sizes; (void)n_in; (void)out_size; (void)ws_size;
  const float* latent = (const float*)d_in[0];
  const float* w_lh   = (const float*)d_in[1];
  const float* b_lh   = (const float*)d_in[2];
  const float* w_lc   = (const float*)d_in[3];
  const float* b_lc   = (const float*)d_in[4];
  const float* w_ih0  = (const float*)d_in[5];
  const float* w_hh0  = (const float*)d_in[6];
  const float* b_ih0  = (const float*)d_in[7];
  const float* b_hh0  = (const float*)d_in[8];
  const float* w_ih1  = (const float*)d_in[9];
  const float* w_hh1  = (const float*)d_in[10];
  const float* b_ih1  = (const float*)d_in[11];
  const float* b_hh1  = (const float*)d_in[12];
  const float* w_out  = (const float*)d_in[13];
  const float* b_out  = (const float*)d_in[14];
  u16* ws = (u16*)d_ws;
  float* out = (float*)d_out;

  auto cvt = [&](const float* src, int off, int ntiles, int kbshift){
    int n = ntiles << (kbshift + 9);
    convert_swizzle<<<dim3((n + 255)/256), dim3(256), 0, stream>>>(src, ws + off, ntiles, kbshift);
  };
  cvt(w_lh,  OFF_LH,  32, 2);
  cvt(w_lc,  OFF_LC,  32, 2);
  cvt(w_ih0, OFF_IH0, 64, 2);
  cvt(w_hh0, OFF_HH0, 64, 3);
  cvt(w_ih1, OFF_IH1, 64, 3);
  cvt(w_hh1, OFF_HH1, 64, 3);
  cvt(w_out, OFF_OUT, 4, 3);

  // reset per-wave flag quads (captured graph node; monotonic from 0 each replay)
  hipMemsetAsync((char*)d_ws + FLAG_B, 0, 256*2*16, stream);

  lstm_fused<<<dim3(256), dim3(512), 0, stream>>>(latent, b_lh, b_lc, b_ih0, b_hh0,
                                                  b_ih1, b_hh1, b_out, ws, ws, out);
}